// Round 1
// baseline (2067.854 us; speedup 1.0000x reference)
//
#include <hip/hip_runtime.h>
#include <math.h>

// OSS / VMamba-style block. B=4, C=64, H=W=64, L=4096, d_inner=512, D_STATE=16.
// All f32. 18 dispatches. Workspace ~151MB with aliasing.

#define DEV static __device__ __forceinline__

DEV float silu_f(float x){ return x / (1.f + __expf(-x)); }

// ---------------- LayerNorm stats (per-batch over C*H*W=262144) ----------------
__global__ __launch_bounds__(256) void ln_stats(const float* __restrict__ x,
                                                float* __restrict__ mu, float* __restrict__ rstd){
  int b = blockIdx.x;
  const float* p = x + (size_t)b*262144;
  double s=0.0, s2=0.0;
  for(int i=threadIdx.x;i<262144;i+=256){ float v=p[i]; s+=v; s2+=(double)v*(double)v; }
  __shared__ double ls[256], ls2[256];
  ls[threadIdx.x]=s; ls2[threadIdx.x]=s2; __syncthreads();
  for(int st=128;st>0;st>>=1){
    if(threadIdx.x<st){ ls[threadIdx.x]+=ls[threadIdx.x+st]; ls2[threadIdx.x]+=ls2[threadIdx.x+st]; }
    __syncthreads();
  }
  if(threadIdx.x==0){
    double m = ls[0]*(1.0/262144.0);
    double var = ls2[0]*(1.0/262144.0) - m*m;
    mu[b]=(float)m; rstd[b]=(float)(1.0/sqrt(var+1e-5));
  }
}

// ---------------- LN1 apply + inproj (64->128) + split, silu on fo2 ----------------
// grid: B*H = 256 blocks, 256 thr. Block handles one (b,h) row of 64 pixels.
__global__ __launch_bounds__(256) void ln1_inproj(const float* __restrict__ x,
    const float* __restrict__ n1w, const float* __restrict__ n1b,
    const float* __restrict__ ipw, const float* __restrict__ ipb,
    const float* __restrict__ mu, const float* __restrict__ rstd,
    float* __restrict__ fo1_raw, float* __restrict__ fo2s){
  int bh = blockIdx.x; int b = bh>>6, h = bh&63;
  __shared__ float xn[64][64];
  __shared__ float wl[128*64];
  float m = mu[b], rs = rstd[b];
  for(int i=threadIdx.x;i<4096;i+=256){
    int c=i>>6, w=i&63;
    size_t sp=(size_t)c*4096 + h*64 + w;
    float v = x[(size_t)b*262144 + sp];
    xn[c][w] = (v-m)*rs*n1w[sp] + n1b[sp];
  }
  for(int i=threadIdx.x;i<8192;i+=256) wl[i]=ipw[i];
  __syncthreads();
  int px = threadIdx.x & 63, ob = (threadIdx.x>>6)*32;
  float acc[32];
  #pragma unroll
  for(int j=0;j<32;j++) acc[j]=0.f;
  for(int c=0;c<64;c++){
    float xv = xn[c][px];
    #pragma unroll
    for(int j=0;j<32;j++) acc[j] = fmaf(wl[(ob+j)*64+c], xv, acc[j]);
  }
  for(int j=0;j<32;j++){
    int o = ob+j;
    float v = acc[j] + ipb[o];
    if(o<64) fo1_raw[((size_t)(b*64+o))*4096 + h*64 + px] = v;
    else     fo2s  [((size_t)(b*64+o-64))*4096 + h*64 + px] = silu_f(v);
  }
}

// ---------------- depthwise 3x3 + silu, writes normal + transposed spatial ----------------
// grid: B*C = 256 blocks
__global__ __launch_bounds__(256) void dwconv_silu_tr(const float* __restrict__ src_,
    const float* __restrict__ dww, const float* __restrict__ dwb,
    float* __restrict__ fo1s, float* __restrict__ fo1t){
  int bc = blockIdx.x; int c = bc & 63;
  const float* src = src_ + (size_t)bc*4096;
  float wk[9];
  #pragma unroll
  for(int k=0;k<9;k++) wk[k]=dww[c*9+k];
  float bias = dwb[c];
  __shared__ float tl[64][65];
  for(int i=threadIdx.x;i<4096;i+=256){
    int h=i>>6, w=i&63;
    float acc=bias;
    #pragma unroll
    for(int kh=0;kh<3;kh++){
      int ih=h+kh-1; if(ih<0||ih>63) continue;
      #pragma unroll
      for(int kw=0;kw<3;kw++){
        int iw=w+kw-1; if(iw<0||iw>63) continue;
        acc += wk[kh*3+kw]*src[ih*64+iw];
      }
    }
    tl[h][w] = silu_f(acc);
  }
  __syncthreads();
  float* ps = fo1s + (size_t)bc*4096;
  float* pt = fo1t + (size_t)bc*4096;
  for(int i=threadIdx.x;i<4096;i+=256){
    ps[i] = tl[i>>6][i&63];
    pt[i] = tl[i&63][i>>6];   // fo1t[q] = value at (h=q%64, w=q/64)  == wf order
  }
}

// ---------------- gather u (B,256,L) channel-major ----------------
__global__ __launch_bounds__(256) void gather_u(const float* __restrict__ fo1s,
    const float* __restrict__ fo1t, float* __restrict__ u){
  int e = blockIdx.x*256 + threadIdx.x;     // 4*256*4096
  int l = e & 4095, cc = (e>>12)&255, b = e>>20;
  int part = cc>>6, c = cc&63;
  const float* s = (part<2)? fo1s : fo1t;
  int idx = (part&1)? (4095-l) : l;
  u[e] = s[((size_t)(b*64+c))*4096 + idx];
}

// ---------------- GEMM: xz = u @ in_w^T  (16384 x 1024 x 256) ----------------
// grid: (256 l-tiles, 16 o-tiles). outputs c-major (B,512,L) into xi0 / z.
__global__ __launch_bounds__(256) void gemm_xz(const float* __restrict__ u,
    const float* __restrict__ in_w, float* __restrict__ xi0, float* __restrict__ z){
  int blk = blockIdx.x; int b = blk>>6, l0 = (blk&63)<<6;
  int o0 = blockIdx.y*64;
  __shared__ __align__(16) float a_t[64][64];
  __shared__ float wch[64][65];
  __shared__ float o_t[64][64];
  int t=threadIdx.x, lq=t>>4, cq=t&15;
  float acc[16];
  #pragma unroll
  for(int j=0;j<16;j++) acc[j]=0.f;
  const float* ub = u + ((size_t)b*256)*4096 + l0;
  for(int kc=0;kc<4;kc++){
    __syncthreads();
    for(int i=t;i<4096;i+=256){ int k=i>>6,l=i&63; a_t[k][l]=ub[(size_t)(kc*64+k)*4096 + l]; }
    for(int i=t;i<4096;i+=256){ int r=i>>6,k=i&63; wch[r][k]=in_w[(o0+r)*256 + kc*64 + k]; }
    __syncthreads();
    for(int k=0;k<64;k++){
      const float4 uv = *(const float4*)&a_t[k][lq<<2];
      float uvf[4]; uvf[0]=uv.x; uvf[1]=uv.y; uvf[2]=uv.z; uvf[3]=uv.w;
      float wv[4];
      #pragma unroll
      for(int j=0;j<4;j++) wv[j]=wch[(cq<<2)+j][k];
      #pragma unroll
      for(int ii=0;ii<4;ii++)
        #pragma unroll
        for(int jj=0;jj<4;jj++)
          acc[ii*4+jj]=fmaf(uvf[ii],wv[jj],acc[ii*4+jj]);
    }
  }
  __syncthreads();
  #pragma unroll
  for(int ii=0;ii<4;ii++)
    #pragma unroll
    for(int jj=0;jj<4;jj++)
      o_t[(cq<<2)+jj][(lq<<2)+ii]=acc[ii*4+jj];
  __syncthreads();
  for(int i=t;i<4096;i+=256){
    int o=i>>6,l=i&63; int og=o0+o;
    float v=o_t[o][l];
    if(og<512) xi0[((size_t)(b*512)+og    )*4096 + l0 + l]=v;
    else       z  [((size_t)(b*512)+og-512)*4096 + l0 + l]=v;
  }
}

// ---------------- causal depthwise conv1d (k=4) + silu, (B,512,L) c-major ----------------
__global__ __launch_bounds__(256) void conv1d_silu(const float* __restrict__ xi0,
    const float* __restrict__ cw, const float* __restrict__ cb, float* __restrict__ xi){
  int e = blockIdx.x*256 + threadIdx.x;   // 4*512*4096
  int l = e & 4095, d = (e>>12)&511;
  float acc = cb[d];
  #pragma unroll
  for(int k=0;k<4;k++){
    int ls = l-3+k;
    if(ls>=0) acc += cw[d*4+k]*xi0[e-3+k];
  }
  xi[e] = silu_f(acc);
}

// ---------------- GEMM: x_dbl = xi @ xproj^T (16384 x 48 x 512), out (B,L,48) ----------------
__global__ __launch_bounds__(256) void gemm_xdbl(const float* __restrict__ xi,
    const float* __restrict__ xpw, float* __restrict__ xdbl){
  int blk=blockIdx.x; int b=blk>>6, l0=(blk&63)<<6;
  __shared__ __align__(16) float a_t[64][64];
  __shared__ float wch[48][65];
  int t=threadIdx.x, lq=t>>4, oq=t&15;
  float acc[12];
  #pragma unroll
  for(int j=0;j<12;j++) acc[j]=0.f;
  for(int kc=0;kc<8;kc++){
    __syncthreads();
    for(int i=t;i<4096;i+=256){ int k=i>>6,l=i&63; a_t[k][l]=xi[((size_t)(b*512)+kc*64+k)*4096 + l0+l]; }
    for(int i=t;i<3072;i+=256){ int r=i>>6,k=i&63; wch[r][k]=xpw[r*512 + kc*64 + k]; }
    __syncthreads();
    for(int k=0;k<64;k++){
      const float4 uv = *(const float4*)&a_t[k][lq<<2];
      float uvf[4]; uvf[0]=uv.x; uvf[1]=uv.y; uvf[2]=uv.z; uvf[3]=uv.w;
      float wv[3];
      #pragma unroll
      for(int j=0;j<3;j++) wv[j]=wch[oq*3+j][k];
      #pragma unroll
      for(int ii=0;ii<4;ii++)
        #pragma unroll
        for(int jj=0;jj<3;jj++)
          acc[ii*3+jj]=fmaf(uvf[ii],wv[jj],acc[ii*3+jj]);
    }
  }
  #pragma unroll
  for(int ii=0;ii<4;ii++)
    #pragma unroll
    for(int jj=0;jj<3;jj++)
      xdbl[((size_t)(b*4096)+l0+(lq<<2)+ii)*48 + oq*3+jj]=acc[ii*3+jj];
}

// ---------------- dt = softplus(xdbl[:, :16] @ dt_w^T + dt_b), out (B,512,L) c-major ----------------
__global__ __launch_bounds__(256) void dtproj(const float* __restrict__ xdbl,
    const float* __restrict__ dtw, const float* __restrict__ dtb, float* __restrict__ dt){
  int blk=blockIdx.x; int b=blk>>6, l0=(blk&63)<<6;
  __shared__ float xl[64][17];
  __shared__ float wl[512][17];
  __shared__ float bl[512];
  for(int i=threadIdx.x;i<1024;i+=256){ int l=i>>4,r=i&15; xl[l][r]=xdbl[((size_t)(b*4096)+l0+l)*48 + r]; }
  for(int i=threadIdx.x;i<8192;i+=256){ int d=i>>4,r=i&15; wl[d][r]=dtw[i]; }
  for(int i=threadIdx.x;i<512;i+=256) bl[i]=dtb[i];
  __syncthreads();
  for(int j=threadIdx.x;j<32768;j+=256){
    int d=j>>6, l=j&63;
    float acc=bl[d];
    #pragma unroll
    for(int r=0;r<16;r++) acc=fmaf(xl[l][r], wl[d][r], acc);
    float sp = (acc>20.f)? acc : log1pf(__expf(acc));
    dt[((size_t)(b*512)+d)*4096 + l0 + l]=sp;
  }
}

// ---------------- selective scan, L=4096. 512 single-wave blocks; wave = 4 d x 16 s ----------------
__global__ __launch_bounds__(64) void m1_scan(
    const float* __restrict__ dt, const float* __restrict__ xi, const float* __restrict__ z,
    const float* __restrict__ xdbl, const float* __restrict__ Alog, const float* __restrict__ Dp,
    float* __restrict__ y){
  int blk=blockIdx.x;
  int b = blk>>7;
  int dbase = (blk&127)*4;
  int lane = threadIdx.x;
  int ds = lane>>4, s = lane&15;
  int d = dbase + ds;
  float A2 = -__expf(Alog[d*16+s]) * 1.44269504088896f;  // exp(dt*A) = exp2(dt*A*log2e)
  float Dv = Dp[d];
  const size_t base_dl = ((size_t)b*512 + dbase)*4096;
  const float* xb = xdbl + (size_t)b*4096*48;
  __shared__ __align__(16) float dtl[2][4][68], xil[2][4][68], zl[2][4][68];
  __shared__ __align__(16) float bcl[2][64][36];
  __shared__ __align__(16) float yl[64][4];
  int row = lane>>4, lq = lane&15;
  float4 rdt, rxi, rz, rbc[8];
  auto issue_loads=[&](int l0){
    size_t o = base_dl + (size_t)row*4096 + l0 + (lq<<2);
    rdt = *(const float4*)(dt + o);
    rxi = *(const float4*)(xi + o);
    rz  = *(const float4*)(z  + o);
    #pragma unroll
    for(int q=0;q<8;q++){
      int e=q*64+lane; int r=e>>3, quad=e&7;
      rbc[q] = *(const float4*)(xb + (size_t)(l0+r)*48 + 16 + (quad<<2));
    }
  };
  auto store_lds=[&](int buf){
    *(float4*)&dtl[buf][row][lq<<2]=rdt;
    *(float4*)&xil[buf][row][lq<<2]=rxi;
    *(float4*)&zl [buf][row][lq<<2]=rz;
    #pragma unroll
    for(int q=0;q<8;q++){
      int e=q*64+lane; int r=e>>3, quad=e&7;
      *(float4*)&bcl[buf][r][quad<<2]=rbc[q];
    }
  };
  float h = 0.f;
  issue_loads(0); store_lds(0); __syncthreads();
  for(int ck=0;ck<64;ck++){
    int buf = ck&1;
    bool more = (ck+1)<64;
    if(more) issue_loads((ck+1)<<6);
    #pragma unroll 4
    for(int j=0;j<64;j++){
      float dtv = dtl[buf][ds][j];
      float xiv = xil[buf][ds][j];
      float zv  = zl [buf][ds][j];
      float Bv  = bcl[buf][j][s];
      float Cv  = bcl[buf][j][16+s];
      float dA  = exp2f(dtv*A2);
      h = fmaf(dA, h, dtv*xiv*Bv);
      float p = h*Cv;
      p += __shfl_xor(p,1,16);
      p += __shfl_xor(p,2,16);
      p += __shfl_xor(p,4,16);
      p += __shfl_xor(p,8,16);
      if(s==0) yl[j][ds] = (p + xiv*Dv) * silu_f(zv);
    }
    __syncthreads();
    int l0 = ck<<6;
    #pragma unroll
    for(int dd=0;dd<4;dd++)
      y[base_dl + (size_t)dd*4096 + l0 + lane] = yl[lane][dd];
    if(more) store_lds(buf^1);
    __syncthreads();
  }
}

// ---------------- fold out_w over the 4 direction groups: W'(64,512) ----------------
__global__ __launch_bounds__(256) void fold_w(const float* __restrict__ ow, float* __restrict__ wf){
  int i = blockIdx.x*256 + threadIdx.x;   // 32768
  if(i>=32768) return;
  int c = i>>9, d2 = i&511;
  wf[i] = ow[(c)*512+d2] + ow[(64+c)*512+d2] + ow[(128+c)*512+d2] + ow[(192+c)*512+d2];
}

// ---------------- GEMM: res = (y @ W'^T) * fo2s ; y (B,512,L), out res (B,64,L) ----------------
__global__ __launch_bounds__(256) void gemm_res(const float* __restrict__ y,
    const float* __restrict__ wf, const float* __restrict__ fo2s, float* __restrict__ res){
  int blk=blockIdx.x; int b=blk>>6, l0=(blk&63)<<6;
  __shared__ __align__(16) float a_t[64][64];
  __shared__ float wch[64][65];
  __shared__ float o_t[64][64];
  int t=threadIdx.x, lq=t>>4, cq=t&15;
  float acc[16];
  #pragma unroll
  for(int j=0;j<16;j++) acc[j]=0.f;
  for(int kc=0;kc<8;kc++){
    __syncthreads();
    for(int i=t;i<4096;i+=256){ int k=i>>6,l=i&63; a_t[k][l]=y[((size_t)(b*512)+kc*64+k)*4096 + l0+l]; }
    for(int i=t;i<4096;i+=256){ int r=i>>6,k=i&63; wch[r][k]=wf[r*512 + kc*64 + k]; }
    __syncthreads();
    for(int k=0;k<64;k++){
      const float4 uv = *(const float4*)&a_t[k][lq<<2];
      float uvf[4]; uvf[0]=uv.x; uvf[1]=uv.y; uvf[2]=uv.z; uvf[3]=uv.w;
      float wv[4];
      #pragma unroll
      for(int j=0;j<4;j++) wv[j]=wch[(cq<<2)+j][k];
      #pragma unroll
      for(int ii=0;ii<4;ii++)
        #pragma unroll
        for(int jj=0;jj<4;jj++)
          acc[ii*4+jj]=fmaf(uvf[ii],wv[jj],acc[ii*4+jj]);
    }
  }
  __syncthreads();
  #pragma unroll
  for(int ii=0;ii<4;ii++)
    #pragma unroll
    for(int jj=0;jj<4;jj++)
      o_t[(cq<<2)+jj][(lq<<2)+ii]=acc[ii*4+jj];
  __syncthreads();
  for(int i=t;i<4096;i+=256){
    int o=i>>6,l=i&63;
    size_t idx=((size_t)(b*64+o))*4096 + l0 + l;
    res[idx]=o_t[o][l]*fo2s[idx];
  }
}

// ---------------- per (b,c) spatial mean ----------------
__global__ __launch_bounds__(256) void colmean(const float* __restrict__ res, float* __restrict__ fm){
  int bc = blockIdx.x;
  const float* p = res + (size_t)bc*4096;
  float s=0;
  for(int i=threadIdx.x;i<4096;i+=256) s+=p[i];
  __shared__ float ls[256];
  ls[threadIdx.x]=s; __syncthreads();
  for(int st=128;st>0;st>>=1){ if(threadIdx.x<st) ls[threadIdx.x]+=ls[threadIdx.x+st]; __syncthreads(); }
  if(threadIdx.x==0) fm[bc]=ls[0]*(1.f/4096.f);
}

// ---------------- tiny mamba2 over channel sequence (L=64, d_model=2, d_inner=4) ----------------
__global__ __launch_bounds__(64) void mamba2_kernel(const float* __restrict__ fm,
    const float* __restrict__ in_w, const float* __restrict__ cw, const float* __restrict__ cb,
    const float* __restrict__ xp, const float* __restrict__ dtw, const float* __restrict__ dtb,
    const float* __restrict__ Alog, const float* __restrict__ Dp, const float* __restrict__ ow,
    float* __restrict__ fsum){
  int b = blockIdx.x; int t = threadIdx.x;   // 0..63
  __shared__ float xi0m[64][4], xim[64][4], dtm[64][4], xbl[64][33], ym[64][4];
  float a0 = fm[b*64+t], a1 = fm[b*64 + 63-t];
  float zreg[4];
  #pragma unroll
  for(int d2=0;d2<4;d2++){
    xi0m[t][d2] = in_w[d2*2+0]*a0 + in_w[d2*2+1]*a1;
    zreg[d2]    = in_w[(4+d2)*2+0]*a0 + in_w[(4+d2)*2+1]*a1;
  }
  __syncthreads();
  float xir[4];
  #pragma unroll
  for(int d2=0;d2<4;d2++){
    float acc=cb[d2];
    #pragma unroll
    for(int k=0;k<4;k++){
      int srow=t-3+k;
      if(srow>=0) acc += cw[d2*4+k]*xi0m[srow][d2];
    }
    xir[d2]=silu_f(acc);
    xim[t][d2]=xir[d2];
  }
  for(int j=0;j<33;j++){
    float acc=0;
    #pragma unroll
    for(int d2=0;d2<4;d2++) acc += xp[j*4+d2]*xir[d2];
    xbl[t][j]=acc;
  }
  #pragma unroll
  for(int d2=0;d2<4;d2++){
    float v = xbl[t][0]*dtw[d2] + dtb[d2];
    dtm[t][d2] = (v>20.f)? v : log1pf(__expf(v));
  }
  __syncthreads();
  int dd=t>>4, s=t&15;
  float A2 = -__expf(Alog[dd*16+s]) * 1.44269504088896f;
  float h=0.f;
  for(int c=0;c<64;c++){
    float dtv=dtm[c][dd];
    float dA=exp2f(dtv*A2);
    h = fmaf(dA, h, dtv*xim[c][dd]*xbl[c][1+s]);
    float p = h*xbl[c][17+s];
    p += __shfl_xor(p,1,16);
    p += __shfl_xor(p,2,16);
    p += __shfl_xor(p,4,16);
    p += __shfl_xor(p,8,16);
    if(s==0) ym[c][dd]=p;
  }
  __syncthreads();
  float os=0.f;
  #pragma unroll
  for(int d2=0;d2<4;d2++){
    float yv = (ym[t][d2] + xim[t][d2]*Dp[d2]) * silu_f(zreg[d2]);
    os += yv * (ow[d2] + ow[4+d2]);
  }
  fsum[b*64+t]=os;
}

// ---------------- foss = res*(1+foc) ; x2 = outproj(foss) + x ----------------
__global__ __launch_bounds__(256) void outproj_kernel(const float* __restrict__ res,
    const float* __restrict__ fsum, const float* __restrict__ opw, const float* __restrict__ opb,
    const float* __restrict__ x, float* __restrict__ x2){
  int bh=blockIdx.x; int b=bh>>6,h=bh&63;
  __shared__ float tile[64][64];
  __shared__ float wl[4096];
  for(int i=threadIdx.x;i<4096;i+=256) wl[i]=opw[i];
  for(int i=threadIdx.x;i<4096;i+=256){
    int c=i>>6,w=i&63;
    tile[c][w]=res[((size_t)(b*64+c))*4096 + h*64 + w]*(1.f+fsum[b*64+c]);
  }
  __syncthreads();
  int px=threadIdx.x&63, og=threadIdx.x>>6;
  float acc[16];
  #pragma unroll
  for(int j=0;j<16;j++) acc[j]=0.f;
  for(int c=0;c<64;c++){
    float v=tile[c][px];
    #pragma unroll
    for(int j=0;j<16;j++) acc[j]=fmaf(wl[(og*16+j)*64+c],v,acc[j]);
  }
  for(int j=0;j<16;j++){
    int o=og*16+j;
    size_t idx=((size_t)(b*64+o))*4096 + h*64 + px;
    x2[idx]=acc[j]+opb[o]+x[idx];
  }
}

// ---------------- LN2 apply + ffn_in (64->256) ----------------
__global__ __launch_bounds__(256) void ffn_in_kernel(const float* __restrict__ x2,
    const float* __restrict__ n2w, const float* __restrict__ n2b,
    const float* __restrict__ fiw, const float* __restrict__ fib,
    const float* __restrict__ mu2, const float* __restrict__ rstd2,
    float* __restrict__ g){
  int bh=blockIdx.x; int b=bh>>6,h=bh&63;
  __shared__ float tile[64][64];
  __shared__ float wl[256*64];
  float m=mu2[b], rs=rstd2[b];
  for(int i=threadIdx.x;i<4096;i+=256){
    int c=i>>6,w=i&63;
    size_t sp=(size_t)c*4096 + h*64 + w;
    tile[c][w]=(x2[(size_t)b*262144+sp]-m)*rs*n2w[sp]+n2b[sp];
  }
  for(int i=threadIdx.x;i<16384;i+=256) wl[i]=fiw[i];
  __syncthreads();
  int px=threadIdx.x&63, og=threadIdx.x>>6;
  for(int half=0;half<2;half++){
    float acc[32];
    #pragma unroll
    for(int j=0;j<32;j++) acc[j]=0.f;
    int ob = half*128 + og*32;
    for(int c=0;c<64;c++){
      float v=tile[c][px];
      #pragma unroll
      for(int j=0;j<32;j++) acc[j]=fmaf(wl[(ob+j)*64+c],v,acc[j]);
    }
    for(int j=0;j<32;j++){
      int o=ob+j;
      g[((size_t)(b*256+o))*4096 + h*64 + px]=acc[j]+fib[o];
    }
  }
}

// ---------------- ffn depthwise 3x3 + gelu-gate ----------------
__global__ __launch_bounds__(256) void ffn_dw_gate(const float* __restrict__ g,
    const float* __restrict__ dww, const float* __restrict__ dwb, float* __restrict__ gm){
  int e = blockIdx.x*256 + threadIdx.x;   // 4*128*4096
  int sp = e & 4095, j = (e>>12)&127, b = e>>19;
  int h = sp>>6, w = sp&63;
  float v[2];
  #pragma unroll
  for(int half=0;half<2;half++){
    int ch = j + half*128;
    const float* gp = g + ((size_t)(b*256+ch))*4096;
    float acc = dwb[ch];
    #pragma unroll
    for(int kh=0;kh<3;kh++){
      int ih=h+kh-1; if(ih<0||ih>63) continue;
      #pragma unroll
      for(int kw=0;kw<3;kw++){
        int iw=w+kw-1; if(iw<0||iw>63) continue;
        acc += dww[ch*9+kh*3+kw]*gp[ih*64+iw];
      }
    }
    v[half]=acc;
  }
  float ge = 0.5f*v[0]*(1.f+erff(v[0]*0.70710678f));
  gm[((size_t)(b*128+j))*4096 + sp] = ge*v[1];
}

// ---------------- ffn_out (128->64) + bias + residual add -> d_out ----------------
__global__ __launch_bounds__(256) void ffn_out_kernel(const float* __restrict__ gm,
    const float* __restrict__ fow, const float* __restrict__ fob,
    const float* __restrict__ x2, float* __restrict__ out){
  int bh=blockIdx.x; int b=bh>>6,h=bh&63;
  __shared__ float tile[128][64];
  __shared__ float wl[64*128];
  for(int i=threadIdx.x;i<8192;i+=256){
    int c=i>>6,w=i&63;
    tile[c][w]=gm[((size_t)(b*128+c))*4096 + h*64 + w];
  }
  for(int i=threadIdx.x;i<8192;i+=256) wl[i]=fow[i];
  __syncthreads();
  int px=threadIdx.x&63, og=threadIdx.x>>6;
  float acc[16];
  #pragma unroll
  for(int j=0;j<16;j++) acc[j]=0.f;
  for(int c=0;c<128;c++){
    float v=tile[c][px];
    #pragma unroll
    for(int j=0;j<16;j++) acc[j]=fmaf(wl[(og*16+j)*128+c],v,acc[j]);
  }
  for(int j=0;j<16;j++){
    int o=og*16+j;
    size_t idx=((size_t)(b*64+o))*4096 + h*64 + px;
    out[idx]=acc[j]+fob[o]+x2[idx];
  }
}

extern "C" void kernel_launch(void* const* d_in, const int* in_sizes, int n_in,
                              void* d_out, int out_size, void* d_ws, size_t ws_size,
                              hipStream_t stream){
  const float* x      = (const float*)d_in[0];
  const float* n1w    = (const float*)d_in[1];
  const float* n1b    = (const float*)d_in[2];
  const float* n2w    = (const float*)d_in[3];
  const float* n2b    = (const float*)d_in[4];
  const float* ipw    = (const float*)d_in[5];
  const float* ipb    = (const float*)d_in[6];
  const float* dww    = (const float*)d_in[7];
  const float* dwb    = (const float*)d_in[8];
  const float* opw    = (const float*)d_in[9];
  const float* opb    = (const float*)d_in[10];
  const float* m1_inw = (const float*)d_in[11];
  const float* m1_cw  = (const float*)d_in[12];
  const float* m1_cb  = (const float*)d_in[13];
  const float* m1_xp  = (const float*)d_in[14];
  const float* m1_dtw = (const float*)d_in[15];
  const float* m1_dtb = (const float*)d_in[16];
  const float* m1_Al  = (const float*)d_in[17];
  const float* m1_D   = (const float*)d_in[18];
  const float* m1_ow  = (const float*)d_in[19];
  const float* m2_inw = (const float*)d_in[20];
  const float* m2_cw  = (const float*)d_in[21];
  const float* m2_cb  = (const float*)d_in[22];
  const float* m2_xp  = (const float*)d_in[23];
  const float* m2_dtw = (const float*)d_in[24];
  const float* m2_dtb = (const float*)d_in[25];
  const float* m2_Al  = (const float*)d_in[26];
  const float* m2_D   = (const float*)d_in[27];
  const float* m2_ow  = (const float*)d_in[28];
  const float* fiw    = (const float*)d_in[29];
  const float* fib    = (const float*)d_in[30];
  const float* fdw    = (const float*)d_in[31];
  const float* fdb    = (const float*)d_in[32];
  const float* fow    = (const float*)d_in[33];
  const float* fob    = (const float*)d_in[34];
  float* out = (float*)d_out;
  float* ws  = (float*)d_ws;

  // workspace layout (floats); total ~39.6M floats (~151MB), aliased.
  float* mu1   = ws + 0;  float* rstd1 = ws + 4;
  float* mu2   = ws + 8;  float* rstd2 = ws + 12;
  float* fmean = ws + 64;    // 256
  float* fsum  = ws + 320;   // 256
  float* wfold = ws + 1024;  // 32768
  float* fo1raw= ws + 36864;           // 1M   (later: res)
  float* fo2s  = fo1raw + 1048576;     // 1M
  float* fo1s  = fo2s   + 1048576;     // 1M
  float* fo1t  = fo1s   + 1048576;     // 1M
  float* ubuf  = fo1t   + 1048576;     // 4M  (u; later dt 8M occupies this region; later g 4M)
  float* dtbuf = ubuf;                 // (B,512,L)
  float* gbuf  = ubuf;                 // (B,256,L)
  float* xi0   = ubuf + 8388608;       // 8M  (later: y)
  float* ybuf  = xi0;
  float* zbuf  = xi0  + 8388608;       // 8M  (later: gm 2M)
  float* gmbuf = zbuf;
  float* xibuf = zbuf + 8388608;       // 8M
  float* xdbl  = xibuf+ 8388608;       // 786432
  float* x2    = xdbl + 786432;        // 1M
  float* res   = fo1raw;

  hipLaunchKernelGGL(ln_stats, dim3(4), dim3(256), 0, stream, x, mu1, rstd1);
  hipLaunchKernelGGL(ln1_inproj, dim3(256), dim3(256), 0, stream,
                     x, n1w, n1b, ipw, ipb, mu1, rstd1, fo1raw, fo2s);
  hipLaunchKernelGGL(dwconv_silu_tr, dim3(256), dim3(256), 0, stream,
                     fo1raw, dww, dwb, fo1s, fo1t);
  hipLaunchKernelGGL(gather_u, dim3(16384), dim3(256), 0, stream, fo1s, fo1t, ubuf);
  hipLaunchKernelGGL(gemm_xz, dim3(256,16), dim3(256), 0, stream, ubuf, m1_inw, xi0, zbuf);
  hipLaunchKernelGGL(conv1d_silu, dim3(32768), dim3(256), 0, stream, xi0, m1_cw, m1_cb, xibuf);
  hipLaunchKernelGGL(gemm_xdbl, dim3(256), dim3(256), 0, stream, xibuf, m1_xp, xdbl);
  hipLaunchKernelGGL(dtproj, dim3(256), dim3(256), 0, stream, xdbl, m1_dtw, m1_dtb, dtbuf);
  hipLaunchKernelGGL(fold_w, dim3(128), dim3(256), 0, stream, m1_ow, wfold);
  hipLaunchKernelGGL(m1_scan, dim3(512), dim3(64), 0, stream,
                     dtbuf, xibuf, zbuf, xdbl, m1_Al, m1_D, ybuf);
  hipLaunchKernelGGL(gemm_res, dim3(256), dim3(256), 0, stream, ybuf, wfold, fo2s, res);
  hipLaunchKernelGGL(colmean, dim3(256), dim3(256), 0, stream, res, fmean);
  hipLaunchKernelGGL(mamba2_kernel, dim3(4), dim3(64), 0, stream,
                     fmean, m2_inw, m2_cw, m2_cb, m2_xp, m2_dtw, m2_dtb, m2_Al, m2_D, m2_ow, fsum);
  hipLaunchKernelGGL(outproj_kernel, dim3(256), dim3(256), 0, stream,
                     res, fsum, opw, opb, x, x2);
  hipLaunchKernelGGL(ln_stats, dim3(4), dim3(256), 0, stream, x2, mu2, rstd2);
  hipLaunchKernelGGL(ffn_in_kernel, dim3(256), dim3(256), 0, stream,
                     x2, n2w, n2b, fiw, fib, mu2, rstd2, gbuf);
  hipLaunchKernelGGL(ffn_dw_gate, dim3(8192), dim3(256), 0, stream, gbuf, fdw, fdb, gmbuf);
  hipLaunchKernelGGL(ffn_out_kernel, dim3(256), dim3(256), 0, stream, gmbuf, fow, fob, x2, out);
}

// Round 2
// 1367.366 us; speedup vs baseline: 1.5123x; 1.5123x over previous
//
#include <hip/hip_runtime.h>
#include <math.h>

// OSS / VMamba-style block. B=4, C=64, H=W=64, L=4096, d_inner=512, D_STATE=16.
// All f32. 18 dispatches. Workspace ~151MB with aliasing.
// R1: m1_scan rewritten — DPP row-rotate reduce (VALU pipe) instead of 4-deep
//     dependent shfl chain (LDS pipe); vectorized LDS layout; emit fused.

#define DEV static __device__ __forceinline__

DEV float silu_f(float x){ return x / (1.f + __expf(-x)); }

// sum across each 16-lane row via DPP row rotations; every lane ends with the sum
DEV float row_sum16(float v){
  v += __int_as_float(__builtin_amdgcn_update_dpp(0, __float_as_int(v), 0x128, 0xF, 0xF, false)); // row_ror:8
  v += __int_as_float(__builtin_amdgcn_update_dpp(0, __float_as_int(v), 0x124, 0xF, 0xF, false)); // row_ror:4
  v += __int_as_float(__builtin_amdgcn_update_dpp(0, __float_as_int(v), 0x122, 0xF, 0xF, false)); // row_ror:2
  v += __int_as_float(__builtin_amdgcn_update_dpp(0, __float_as_int(v), 0x121, 0xF, 0xF, false)); // row_ror:1
  return v;
}

// ---------------- LayerNorm stats (per-batch over C*H*W=262144) ----------------
__global__ __launch_bounds__(256) void ln_stats(const float* __restrict__ x,
                                                float* __restrict__ mu, float* __restrict__ rstd){
  int b = blockIdx.x;
  const float* p = x + (size_t)b*262144;
  double s=0.0, s2=0.0;
  for(int i=threadIdx.x;i<262144;i+=256){ float v=p[i]; s+=v; s2+=(double)v*(double)v; }
  __shared__ double ls[256], ls2[256];
  ls[threadIdx.x]=s; ls2[threadIdx.x]=s2; __syncthreads();
  for(int st=128;st>0;st>>=1){
    if(threadIdx.x<st){ ls[threadIdx.x]+=ls[threadIdx.x+st]; ls2[threadIdx.x]+=ls2[threadIdx.x+st]; }
    __syncthreads();
  }
  if(threadIdx.x==0){
    double m = ls[0]*(1.0/262144.0);
    double var = ls2[0]*(1.0/262144.0) - m*m;
    mu[b]=(float)m; rstd[b]=(float)(1.0/sqrt(var+1e-5));
  }
}

// ---------------- LN1 apply + inproj (64->128) + split, silu on fo2 ----------------
__global__ __launch_bounds__(256) void ln1_inproj(const float* __restrict__ x,
    const float* __restrict__ n1w, const float* __restrict__ n1b,
    const float* __restrict__ ipw, const float* __restrict__ ipb,
    const float* __restrict__ mu, const float* __restrict__ rstd,
    float* __restrict__ fo1_raw, float* __restrict__ fo2s){
  int bh = blockIdx.x; int b = bh>>6, h = bh&63;
  __shared__ float xn[64][64];
  __shared__ float wl[128*64];
  float m = mu[b], rs = rstd[b];
  for(int i=threadIdx.x;i<4096;i+=256){
    int c=i>>6, w=i&63;
    size_t sp=(size_t)c*4096 + h*64 + w;
    float v = x[(size_t)b*262144 + sp];
    xn[c][w] = (v-m)*rs*n1w[sp] + n1b[sp];
  }
  for(int i=threadIdx.x;i<8192;i+=256) wl[i]=ipw[i];
  __syncthreads();
  int px = threadIdx.x & 63, ob = (threadIdx.x>>6)*32;
  float acc[32];
  #pragma unroll
  for(int j=0;j<32;j++) acc[j]=0.f;
  for(int c=0;c<64;c++){
    float xv = xn[c][px];
    #pragma unroll
    for(int j=0;j<32;j++) acc[j] = fmaf(wl[(ob+j)*64+c], xv, acc[j]);
  }
  for(int j=0;j<32;j++){
    int o = ob+j;
    float v = acc[j] + ipb[o];
    if(o<64) fo1_raw[((size_t)(b*64+o))*4096 + h*64 + px] = v;
    else     fo2s  [((size_t)(b*64+o-64))*4096 + h*64 + px] = silu_f(v);
  }
}

// ---------------- depthwise 3x3 + silu, writes normal + transposed spatial ----------------
__global__ __launch_bounds__(256) void dwconv_silu_tr(const float* __restrict__ src_,
    const float* __restrict__ dww, const float* __restrict__ dwb,
    float* __restrict__ fo1s, float* __restrict__ fo1t){
  int bc = blockIdx.x; int c = bc & 63;
  const float* src = src_ + (size_t)bc*4096;
  float wk[9];
  #pragma unroll
  for(int k=0;k<9;k++) wk[k]=dww[c*9+k];
  float bias = dwb[c];
  __shared__ float tl[64][65];
  for(int i=threadIdx.x;i<4096;i+=256){
    int h=i>>6, w=i&63;
    float acc=bias;
    #pragma unroll
    for(int kh=0;kh<3;kh++){
      int ih=h+kh-1; if(ih<0||ih>63) continue;
      #pragma unroll
      for(int kw=0;kw<3;kw++){
        int iw=w+kw-1; if(iw<0||iw>63) continue;
        acc += wk[kh*3+kw]*src[ih*64+iw];
      }
    }
    tl[h][w] = silu_f(acc);
  }
  __syncthreads();
  float* ps = fo1s + (size_t)bc*4096;
  float* pt = fo1t + (size_t)bc*4096;
  for(int i=threadIdx.x;i<4096;i+=256){
    ps[i] = tl[i>>6][i&63];
    pt[i] = tl[i&63][i>>6];
  }
}

// ---------------- gather u (B,256,L) channel-major ----------------
__global__ __launch_bounds__(256) void gather_u(const float* __restrict__ fo1s,
    const float* __restrict__ fo1t, float* __restrict__ u){
  int e = blockIdx.x*256 + threadIdx.x;     // 4*256*4096
  int l = e & 4095, cc = (e>>12)&255, b = e>>20;
  int part = cc>>6, c = cc&63;
  const float* s = (part<2)? fo1s : fo1t;
  int idx = (part&1)? (4095-l) : l;
  u[e] = s[((size_t)(b*64+c))*4096 + idx];
}

// ---------------- GEMM: xz = u @ in_w^T  (16384 x 1024 x 256) ----------------
__global__ __launch_bounds__(256) void gemm_xz(const float* __restrict__ u,
    const float* __restrict__ in_w, float* __restrict__ xi0, float* __restrict__ z){
  int blk = blockIdx.x; int b = blk>>6, l0 = (blk&63)<<6;
  int o0 = blockIdx.y*64;
  __shared__ __align__(16) float a_t[64][64];
  __shared__ float wch[64][65];
  __shared__ float o_t[64][64];
  int t=threadIdx.x, lq=t>>4, cq=t&15;
  float acc[16];
  #pragma unroll
  for(int j=0;j<16;j++) acc[j]=0.f;
  const float* ub = u + ((size_t)b*256)*4096 + l0;
  for(int kc=0;kc<4;kc++){
    __syncthreads();
    for(int i=t;i<4096;i+=256){ int k=i>>6,l=i&63; a_t[k][l]=ub[(size_t)(kc*64+k)*4096 + l]; }
    for(int i=t;i<4096;i+=256){ int r=i>>6,k=i&63; wch[r][k]=in_w[(o0+r)*256 + kc*64 + k]; }
    __syncthreads();
    for(int k=0;k<64;k++){
      const float4 uv = *(const float4*)&a_t[k][lq<<2];
      float uvf[4]; uvf[0]=uv.x; uvf[1]=uv.y; uvf[2]=uv.z; uvf[3]=uv.w;
      float wv[4];
      #pragma unroll
      for(int j=0;j<4;j++) wv[j]=wch[(cq<<2)+j][k];
      #pragma unroll
      for(int ii=0;ii<4;ii++)
        #pragma unroll
        for(int jj=0;jj<4;jj++)
          acc[ii*4+jj]=fmaf(uvf[ii],wv[jj],acc[ii*4+jj]);
    }
  }
  __syncthreads();
  #pragma unroll
  for(int ii=0;ii<4;ii++)
    #pragma unroll
    for(int jj=0;jj<4;jj++)
      o_t[(cq<<2)+jj][(lq<<2)+ii]=acc[ii*4+jj];
  __syncthreads();
  for(int i=t;i<4096;i+=256){
    int o=i>>6,l=i&63; int og=o0+o;
    float v=o_t[o][l];
    if(og<512) xi0[((size_t)(b*512)+og    )*4096 + l0 + l]=v;
    else       z  [((size_t)(b*512)+og-512)*4096 + l0 + l]=v;
  }
}

// ---------------- causal depthwise conv1d (k=4) + silu, (B,512,L) c-major ----------------
__global__ __launch_bounds__(256) void conv1d_silu(const float* __restrict__ xi0,
    const float* __restrict__ cw, const float* __restrict__ cb, float* __restrict__ xi){
  int e = blockIdx.x*256 + threadIdx.x;   // 4*512*4096
  int l = e & 4095, d = (e>>12)&511;
  float acc = cb[d];
  #pragma unroll
  for(int k=0;k<4;k++){
    int ls = l-3+k;
    if(ls>=0) acc += cw[d*4+k]*xi0[e-3+k];
  }
  xi[e] = silu_f(acc);
}

// ---------------- GEMM: x_dbl = xi @ xproj^T (16384 x 48 x 512), out (B,L,48) ----------------
__global__ __launch_bounds__(256) void gemm_xdbl(const float* __restrict__ xi,
    const float* __restrict__ xpw, float* __restrict__ xdbl){
  int blk=blockIdx.x; int b=blk>>6, l0=(blk&63)<<6;
  __shared__ __align__(16) float a_t[64][64];
  __shared__ float wch[48][65];
  int t=threadIdx.x, lq=t>>4, oq=t&15;
  float acc[12];
  #pragma unroll
  for(int j=0;j<12;j++) acc[j]=0.f;
  for(int kc=0;kc<8;kc++){
    __syncthreads();
    for(int i=t;i<4096;i+=256){ int k=i>>6,l=i&63; a_t[k][l]=xi[((size_t)(b*512)+kc*64+k)*4096 + l0+l]; }
    for(int i=t;i<3072;i+=256){ int r=i>>6,k=i&63; wch[r][k]=xpw[r*512 + kc*64 + k]; }
    __syncthreads();
    for(int k=0;k<64;k++){
      const float4 uv = *(const float4*)&a_t[k][lq<<2];
      float uvf[4]; uvf[0]=uv.x; uvf[1]=uv.y; uvf[2]=uv.z; uvf[3]=uv.w;
      float wv[3];
      #pragma unroll
      for(int j=0;j<3;j++) wv[j]=wch[oq*3+j][k];
      #pragma unroll
      for(int ii=0;ii<4;ii++)
        #pragma unroll
        for(int jj=0;jj<3;jj++)
          acc[ii*3+jj]=fmaf(uvf[ii],wv[jj],acc[ii*3+jj]);
    }
  }
  #pragma unroll
  for(int ii=0;ii<4;ii++)
    #pragma unroll
    for(int jj=0;jj<3;jj++)
      xdbl[((size_t)(b*4096)+l0+(lq<<2)+ii)*48 + oq*3+jj]=acc[ii*3+jj];
}

// ---------------- dt = softplus(xdbl[:, :16] @ dt_w^T + dt_b), out (B,512,L) c-major ----------------
__global__ __launch_bounds__(256) void dtproj(const float* __restrict__ xdbl,
    const float* __restrict__ dtw, const float* __restrict__ dtb, float* __restrict__ dt){
  int blk=blockIdx.x; int b=blk>>6, l0=(blk&63)<<6;
  __shared__ float xl[64][17];
  __shared__ float wl[512][17];
  __shared__ float bl[512];
  for(int i=threadIdx.x;i<1024;i+=256){ int l=i>>4,r=i&15; xl[l][r]=xdbl[((size_t)(b*4096)+l0+l)*48 + r]; }
  for(int i=threadIdx.x;i<8192;i+=256){ int d=i>>4,r=i&15; wl[d][r]=dtw[i]; }
  for(int i=threadIdx.x;i<512;i+=256) bl[i]=dtb[i];
  __syncthreads();
  for(int j=threadIdx.x;j<32768;j+=256){
    int d=j>>6, l=j&63;
    float acc=bl[d];
    #pragma unroll
    for(int r=0;r<16;r++) acc=fmaf(xl[l][r], wl[d][r], acc);
    float sp = (acc>20.f)? acc : log1pf(__expf(acc));
    dt[((size_t)(b*512)+d)*4096 + l0 + l]=sp;
  }
}

// ---------------- selective scan, L=4096. 512 single-wave blocks; wave = 4 d x 16 s ----------------
// R1 rewrite: DPP row-rotate reduce (VALU), interleaved LDS layouts, float4 y-partials.
__global__ __launch_bounds__(64) void m1_scan(
    const float* __restrict__ dt, const float* __restrict__ xi, const float* __restrict__ z,
    const float* __restrict__ xdbl, const float* __restrict__ Alog, const float* __restrict__ Dp,
    float* __restrict__ y){
  int blk=blockIdx.x;
  int b = blk>>7;
  int dbase = (blk&127)*4;
  int lane = threadIdx.x;
  int ds = lane>>4, s = lane&15;
  int d = dbase + ds;
  float A2 = -__expf(Alog[d*16+s]) * 1.44269504088896f;  // exp(dt*A) = exp2(dt*A*log2e)
  float D4[4];
  #pragma unroll
  for(int dd=0;dd<4;dd++) D4[dd]=Dp[dbase+dd];
  const size_t base_dl = ((size_t)b*512 + dbase)*4096;
  const float* xb = xdbl + (size_t)b*4096*48;

  // dxl: (dt,xi) interleaved pairs, row stride 136 (banks disjoint per ds)
  // bcl4: slot s2 holds {B[j][2s2], C[j][2s2], B[j][2s2+1], C[j][2s2+1]}, row stride 9*16B
  // pl4: y-partials, one float4 (4 steps) per (j4, d)
  __shared__ __align__(16) float  dxl[2][4][136];
  __shared__ __align__(16) float  zl [2][4][68];
  __shared__ __align__(16) float4 bcl4[2][64][9];
  __shared__ __align__(16) float4 pl4[16][4];

  int row = lane>>4, c4 = (lane&15)<<2;
  float4 rdt, rxi, rz;
  float2 rb[8], rc[8];

  auto issue_loads=[&](int l0){
    size_t o = base_dl + (size_t)row*4096 + l0 + c4;
    rdt = *(const float4*)(dt + o);
    rxi = *(const float4*)(xi + o);
    rz  = *(const float4*)(z  + o);
    #pragma unroll
    for(int q=0;q<8;q++){
      int r = q*8 + (lane>>3), s2 = (lane&7)*2;
      const float* rowp = xb + (size_t)(l0+r)*48;
      rb[q] = *(const float2*)(rowp + 16 + s2);
      rc[q] = *(const float2*)(rowp + 32 + s2);
    }
  };
  auto store_lds=[&](int buf){
    *(float4*)&dxl[buf][row][2*c4]   = make_float4(rdt.x, rxi.x, rdt.y, rxi.y);
    *(float4*)&dxl[buf][row][2*c4+4] = make_float4(rdt.z, rxi.z, rdt.w, rxi.w);
    *(float4*)&zl[buf][row][c4]      = rz;
    #pragma unroll
    for(int q=0;q<8;q++){
      int r = q*8 + (lane>>3), s2h = lane&7;
      bcl4[buf][r][s2h] = make_float4(rb[q].x, rc[q].x, rb[q].y, rc[q].y);
    }
  };

  float h = 0.f;
  issue_loads(0); store_lds(0); __syncthreads();
  for(int ck=0;ck<64;ck++){
    int buf = ck&1;
    bool more = (ck+1)<64;
    if(more) issue_loads((ck+1)<<6);
    const char* bcbase = (const char*)&bcl4[buf][0][s>>1] + (s&1)*8;
    #pragma unroll 4
    for(int j4=0;j4<16;j4++){
      const float4 a  = *(const float4*)&dxl[buf][ds][8*j4];
      const float4 c2 = *(const float4*)&dxl[buf][ds][8*j4+4];
      float4 pacc;
      {
        float2 bc = *(const float2*)(bcbase + (size_t)(4*j4+0)*144);
        float dA = exp2f(a.x*A2);
        h = fmaf(dA, h, a.x*a.y*bc.x);
        pacc.x = row_sum16(h*bc.y);
      }
      {
        float2 bc = *(const float2*)(bcbase + (size_t)(4*j4+1)*144);
        float dA = exp2f(a.z*A2);
        h = fmaf(dA, h, a.z*a.w*bc.x);
        pacc.y = row_sum16(h*bc.y);
      }
      {
        float2 bc = *(const float2*)(bcbase + (size_t)(4*j4+2)*144);
        float dA = exp2f(c2.x*A2);
        h = fmaf(dA, h, c2.x*c2.y*bc.x);
        pacc.z = row_sum16(h*bc.y);
      }
      {
        float2 bc = *(const float2*)(bcbase + (size_t)(4*j4+3)*144);
        float dA = exp2f(c2.z*A2);
        h = fmaf(dA, h, c2.z*c2.w*bc.x);
        pacc.w = row_sum16(h*bc.y);
      }
      if(s==15) pl4[j4][ds] = pacc;
    }
    __syncthreads();
    int l0 = ck<<6;
    int t = lane;
    #pragma unroll
    for(int dd=0;dd<4;dd++){
      float ps  = ((const float*)&pl4[t>>2][dd])[t&3];
      float xiv = dxl[buf][dd][2*t+1];
      float zv  = zl[buf][dd][t];
      y[base_dl + (size_t)dd*4096 + l0 + t] = (ps + xiv*D4[dd]) * silu_f(zv);
    }
    if(more) store_lds(buf^1);
    __syncthreads();
  }
}

// ---------------- fold out_w over the 4 direction groups: W'(64,512) ----------------
__global__ __launch_bounds__(256) void fold_w(const float* __restrict__ ow, float* __restrict__ wf){
  int i = blockIdx.x*256 + threadIdx.x;   // 32768
  if(i>=32768) return;
  int c = i>>9, d2 = i&511;
  wf[i] = ow[(c)*512+d2] + ow[(64+c)*512+d2] + ow[(128+c)*512+d2] + ow[(192+c)*512+d2];
}

// ---------------- GEMM: res = (y @ W'^T) * fo2s ; y (B,512,L), out res (B,64,L) ----------------
__global__ __launch_bounds__(256) void gemm_res(const float* __restrict__ y,
    const float* __restrict__ wf, const float* __restrict__ fo2s, float* __restrict__ res){
  int blk=blockIdx.x; int b=blk>>6, l0=(blk&63)<<6;
  __shared__ __align__(16) float a_t[64][64];
  __shared__ float wch[64][65];
  __shared__ float o_t[64][64];
  int t=threadIdx.x, lq=t>>4, cq=t&15;
  float acc[16];
  #pragma unroll
  for(int j=0;j<16;j++) acc[j]=0.f;
  for(int kc=0;kc<8;kc++){
    __syncthreads();
    for(int i=t;i<4096;i+=256){ int k=i>>6,l=i&63; a_t[k][l]=y[((size_t)(b*512)+kc*64+k)*4096 + l0+l]; }
    for(int i=t;i<4096;i+=256){ int r=i>>6,k=i&63; wch[r][k]=wf[r*512 + kc*64 + k]; }
    __syncthreads();
    for(int k=0;k<64;k++){
      const float4 uv = *(const float4*)&a_t[k][lq<<2];
      float uvf[4]; uvf[0]=uv.x; uvf[1]=uv.y; uvf[2]=uv.z; uvf[3]=uv.w;
      float wv[4];
      #pragma unroll
      for(int j=0;j<4;j++) wv[j]=wch[(cq<<2)+j][k];
      #pragma unroll
      for(int ii=0;ii<4;ii++)
        #pragma unroll
        for(int jj=0;jj<4;jj++)
          acc[ii*4+jj]=fmaf(uvf[ii],wv[jj],acc[ii*4+jj]);
    }
  }
  __syncthreads();
  #pragma unroll
  for(int ii=0;ii<4;ii++)
    #pragma unroll
    for(int jj=0;jj<4;jj++)
      o_t[(cq<<2)+jj][(lq<<2)+ii]=acc[ii*4+jj];
  __syncthreads();
  for(int i=t;i<4096;i+=256){
    int o=i>>6,l=i&63;
    size_t idx=((size_t)(b*64+o))*4096 + l0 + l;
    res[idx]=o_t[o][l]*fo2s[idx];
  }
}

// ---------------- per (b,c) spatial mean ----------------
__global__ __launch_bounds__(256) void colmean(const float* __restrict__ res, float* __restrict__ fm){
  int bc = blockIdx.x;
  const float* p = res + (size_t)bc*4096;
  float s=0;
  for(int i=threadIdx.x;i<4096;i+=256) s+=p[i];
  __shared__ float ls[256];
  ls[threadIdx.x]=s; __syncthreads();
  for(int st=128;st>0;st>>=1){ if(threadIdx.x<st) ls[threadIdx.x]+=ls[threadIdx.x+st]; __syncthreads(); }
  if(threadIdx.x==0) fm[bc]=ls[0]*(1.f/4096.f);
}

// ---------------- tiny mamba2 over channel sequence (L=64, d_model=2, d_inner=4) ----------------
__global__ __launch_bounds__(64) void mamba2_kernel(const float* __restrict__ fm,
    const float* __restrict__ in_w, const float* __restrict__ cw, const float* __restrict__ cb,
    const float* __restrict__ xp, const float* __restrict__ dtw, const float* __restrict__ dtb,
    const float* __restrict__ Alog, const float* __restrict__ Dp, const float* __restrict__ ow,
    float* __restrict__ fsum){
  int b = blockIdx.x; int t = threadIdx.x;   // 0..63
  __shared__ float xi0m[64][4], xim[64][4], dtm[64][4], xbl[64][33], ym[64][4];
  float a0 = fm[b*64+t], a1 = fm[b*64 + 63-t];
  float zreg[4];
  #pragma unroll
  for(int d2=0;d2<4;d2++){
    xi0m[t][d2] = in_w[d2*2+0]*a0 + in_w[d2*2+1]*a1;
    zreg[d2]    = in_w[(4+d2)*2+0]*a0 + in_w[(4+d2)*2+1]*a1;
  }
  __syncthreads();
  float xir[4];
  #pragma unroll
  for(int d2=0;d2<4;d2++){
    float acc=cb[d2];
    #pragma unroll
    for(int k=0;k<4;k++){
      int srow=t-3+k;
      if(srow>=0) acc += cw[d2*4+k]*xi0m[srow][d2];
    }
    xir[d2]=silu_f(acc);
    xim[t][d2]=xir[d2];
  }
  for(int j=0;j<33;j++){
    float acc=0;
    #pragma unroll
    for(int d2=0;d2<4;d2++) acc += xp[j*4+d2]*xir[d2];
    xbl[t][j]=acc;
  }
  #pragma unroll
  for(int d2=0;d2<4;d2++){
    float v = xbl[t][0]*dtw[d2] + dtb[d2];
    dtm[t][d2] = (v>20.f)? v : log1pf(__expf(v));
  }
  __syncthreads();
  int dd=t>>4, s=t&15;
  float A2 = -__expf(Alog[dd*16+s]) * 1.44269504088896f;
  float h=0.f;
  for(int c=0;c<64;c++){
    float dtv=dtm[c][dd];
    float dA=exp2f(dtv*A2);
    h = fmaf(dA, h, dtv*xim[c][dd]*xbl[c][1+s]);
    float p = h*xbl[c][17+s];
    p += __shfl_xor(p,1,16);
    p += __shfl_xor(p,2,16);
    p += __shfl_xor(p,4,16);
    p += __shfl_xor(p,8,16);
    if(s==0) ym[c][dd]=p;
  }
  __syncthreads();
  float os=0.f;
  #pragma unroll
  for(int d2=0;d2<4;d2++){
    float yv = (ym[t][d2] + xim[t][d2]*Dp[d2]) * silu_f(zreg[d2]);
    os += yv * (ow[d2] + ow[4+d2]);
  }
  fsum[b*64+t]=os;
}

// ---------------- foss = res*(1+foc) ; x2 = outproj(foss) + x ----------------
__global__ __launch_bounds__(256) void outproj_kernel(const float* __restrict__ res,
    const float* __restrict__ fsum, const float* __restrict__ opw, const float* __restrict__ opb,
    const float* __restrict__ x, float* __restrict__ x2){
  int bh=blockIdx.x; int b=bh>>6,h=bh&63;
  __shared__ float tile[64][64];
  __shared__ float wl[4096];
  for(int i=threadIdx.x;i<4096;i+=256) wl[i]=opw[i];
  for(int i=threadIdx.x;i<4096;i+=256){
    int c=i>>6,w=i&63;
    tile[c][w]=res[((size_t)(b*64+c))*4096 + h*64 + w]*(1.f+fsum[b*64+c]);
  }
  __syncthreads();
  int px=threadIdx.x&63, og=threadIdx.x>>6;
  float acc[16];
  #pragma unroll
  for(int j=0;j<16;j++) acc[j]=0.f;
  for(int c=0;c<64;c++){
    float v=tile[c][px];
    #pragma unroll
    for(int j=0;j<16;j++) acc[j]=fmaf(wl[(og*16+j)*64+c],v,acc[j]);
  }
  for(int j=0;j<16;j++){
    int o=og*16+j;
    size_t idx=((size_t)(b*64+o))*4096 + h*64 + px;
    x2[idx]=acc[j]+opb[o]+x[idx];
  }
}

// ---------------- LN2 apply + ffn_in (64->256) ----------------
__global__ __launch_bounds__(256) void ffn_in_kernel(const float* __restrict__ x2,
    const float* __restrict__ n2w, const float* __restrict__ n2b,
    const float* __restrict__ fiw, const float* __restrict__ fib,
    const float* __restrict__ mu2, const float* __restrict__ rstd2,
    float* __restrict__ g){
  int bh=blockIdx.x; int b=bh>>6,h=bh&63;
  __shared__ float tile[64][64];
  __shared__ float wl[256*64];
  float m=mu2[b], rs=rstd2[b];
  for(int i=threadIdx.x;i<4096;i+=256){
    int c=i>>6,w=i&63;
    size_t sp=(size_t)c*4096 + h*64 + w;
    tile[c][w]=(x2[(size_t)b*262144+sp]-m)*rs*n2w[sp]+n2b[sp];
  }
  for(int i=threadIdx.x;i<16384;i+=256) wl[i]=fiw[i];
  __syncthreads();
  int px=threadIdx.x&63, og=threadIdx.x>>6;
  for(int half=0;half<2;half++){
    float acc[32];
    #pragma unroll
    for(int j=0;j<32;j++) acc[j]=0.f;
    int ob = half*128 + og*32;
    for(int c=0;c<64;c++){
      float v=tile[c][px];
      #pragma unroll
      for(int j=0;j<32;j++) acc[j]=fmaf(wl[(ob+j)*64+c],v,acc[j]);
    }
    for(int j=0;j<32;j++){
      int o=ob+j;
      g[((size_t)(b*256+o))*4096 + h*64 + px]=acc[j]+fib[o];
    }
  }
}

// ---------------- ffn depthwise 3x3 + gelu-gate ----------------
__global__ __launch_bounds__(256) void ffn_dw_gate(const float* __restrict__ g,
    const float* __restrict__ dww, const float* __restrict__ dwb, float* __restrict__ gm){
  int e = blockIdx.x*256 + threadIdx.x;   // 4*128*4096
  int sp = e & 4095, j = (e>>12)&127, b = e>>19;
  int h = sp>>6, w = sp&63;
  float v[2];
  #pragma unroll
  for(int half=0;half<2;half++){
    int ch = j + half*128;
    const float* gp = g + ((size_t)(b*256+ch))*4096;
    float acc = dwb[ch];
    #pragma unroll
    for(int kh=0;kh<3;kh++){
      int ih=h+kh-1; if(ih<0||ih>63) continue;
      #pragma unroll
      for(int kw=0;kw<3;kw++){
        int iw=w+kw-1; if(iw<0||iw>63) continue;
        acc += dww[ch*9+kh*3+kw]*gp[ih*64+iw];
      }
    }
    v[half]=acc;
  }
  float ge = 0.5f*v[0]*(1.f+erff(v[0]*0.70710678f));
  gm[((size_t)(b*128+j))*4096 + sp] = ge*v[1];
}

// ---------------- ffn_out (128->64) + bias + residual add -> d_out ----------------
__global__ __launch_bounds__(256) void ffn_out_kernel(const float* __restrict__ gm,
    const float* __restrict__ fow, const float* __restrict__ fob,
    const float* __restrict__ x2, float* __restrict__ out){
  int bh=blockIdx.x; int b=bh>>6,h=bh&63;
  __shared__ float tile[128][64];
  __shared__ float wl[64*128];
  for(int i=threadIdx.x;i<8192;i+=256){
    int c=i>>6,w=i&63;
    tile[c][w]=gm[((size_t)(b*128+c))*4096 + h*64 + w];
  }
  for(int i=threadIdx.x;i<8192;i+=256) wl[i]=fow[i];
  __syncthreads();
  int px=threadIdx.x&63, og=threadIdx.x>>6;
  float acc[16];
  #pragma unroll
  for(int j=0;j<16;j++) acc[j]=0.f;
  for(int c=0;c<128;c++){
    float v=tile[c][px];
    #pragma unroll
    for(int j=0;j<16;j++) acc[j]=fmaf(wl[(og*16+j)*128+c],v,acc[j]);
  }
  for(int j=0;j<16;j++){
    int o=og*16+j;
    size_t idx=((size_t)(b*64+o))*4096 + h*64 + px;
    out[idx]=acc[j]+fob[o]+x2[idx];
  }
}

extern "C" void kernel_launch(void* const* d_in, const int* in_sizes, int n_in,
                              void* d_out, int out_size, void* d_ws, size_t ws_size,
                              hipStream_t stream){
  const float* x      = (const float*)d_in[0];
  const float* n1w    = (const float*)d_in[1];
  const float* n1b    = (const float*)d_in[2];
  const float* n2w    = (const float*)d_in[3];
  const float* n2b    = (const float*)d_in[4];
  const float* ipw    = (const float*)d_in[5];
  const float* ipb    = (const float*)d_in[6];
  const float* dww    = (const float*)d_in[7];
  const float* dwb    = (const float*)d_in[8];
  const float* opw    = (const float*)d_in[9];
  const float* opb    = (const float*)d_in[10];
  const float* m1_inw = (const float*)d_in[11];
  const float* m1_cw  = (const float*)d_in[12];
  const float* m1_cb  = (const float*)d_in[13];
  const float* m1_xp  = (const float*)d_in[14];
  const float* m1_dtw = (const float*)d_in[15];
  const float* m1_dtb = (const float*)d_in[16];
  const float* m1_Al  = (const float*)d_in[17];
  const float* m1_D   = (const float*)d_in[18];
  const float* m1_ow  = (const float*)d_in[19];
  const float* m2_inw = (const float*)d_in[20];
  const float* m2_cw  = (const float*)d_in[21];
  const float* m2_cb  = (const float*)d_in[22];
  const float* m2_xp  = (const float*)d_in[23];
  const float* m2_dtw = (const float*)d_in[24];
  const float* m2_dtb = (const float*)d_in[25];
  const float* m2_Al  = (const float*)d_in[26];
  const float* m2_D   = (const float*)d_in[27];
  const float* m2_ow  = (const float*)d_in[28];
  const float* fiw    = (const float*)d_in[29];
  const float* fib    = (const float*)d_in[30];
  const float* fdw    = (const float*)d_in[31];
  const float* fdb    = (const float*)d_in[32];
  const float* fow    = (const float*)d_in[33];
  const float* fob    = (const float*)d_in[34];
  float* out = (float*)d_out;
  float* ws  = (float*)d_ws;

  // workspace layout (floats); total ~39.6M floats (~151MB), aliased.
  float* mu1   = ws + 0;  float* rstd1 = ws + 4;
  float* mu2   = ws + 8;  float* rstd2 = ws + 12;
  float* fmean = ws + 64;    // 256
  float* fsum  = ws + 320;   // 256
  float* wfold = ws + 1024;  // 32768
  float* fo1raw= ws + 36864;           // 1M   (later: res)
  float* fo2s  = fo1raw + 1048576;     // 1M
  float* fo1s  = fo2s   + 1048576;     // 1M
  float* fo1t  = fo1s   + 1048576;     // 1M
  float* ubuf  = fo1t   + 1048576;     // 4M  (u; later dt 8M occupies this region; later g 4M)
  float* dtbuf = ubuf;                 // (B,512,L)
  float* gbuf  = ubuf;                 // (B,256,L)
  float* xi0   = ubuf + 8388608;       // 8M  (later: y)
  float* ybuf  = xi0;
  float* zbuf  = xi0  + 8388608;       // 8M  (later: gm 2M)
  float* gmbuf = zbuf;
  float* xibuf = zbuf + 8388608;       // 8M
  float* xdbl  = xibuf+ 8388608;       // 786432
  float* x2    = xdbl + 786432;        // 1M
  float* res   = fo1raw;

  hipLaunchKernelGGL(ln_stats, dim3(4), dim3(256), 0, stream, x, mu1, rstd1);
  hipLaunchKernelGGL(ln1_inproj, dim3(256), dim3(256), 0, stream,
                     x, n1w, n1b, ipw, ipb, mu1, rstd1, fo1raw, fo2s);
  hipLaunchKernelGGL(dwconv_silu_tr, dim3(256), dim3(256), 0, stream,
                     fo1raw, dww, dwb, fo1s, fo1t);
  hipLaunchKernelGGL(gather_u, dim3(16384), dim3(256), 0, stream, fo1s, fo1t, ubuf);
  hipLaunchKernelGGL(gemm_xz, dim3(256,16), dim3(256), 0, stream, ubuf, m1_inw, xi0, zbuf);
  hipLaunchKernelGGL(conv1d_silu, dim3(32768), dim3(256), 0, stream, xi0, m1_cw, m1_cb, xibuf);
  hipLaunchKernelGGL(gemm_xdbl, dim3(256), dim3(256), 0, stream, xibuf, m1_xp, xdbl);
  hipLaunchKernelGGL(dtproj, dim3(256), dim3(256), 0, stream, xdbl, m1_dtw, m1_dtb, dtbuf);
  hipLaunchKernelGGL(fold_w, dim3(128), dim3(256), 0, stream, m1_ow, wfold);
  hipLaunchKernelGGL(m1_scan, dim3(512), dim3(64), 0, stream,
                     dtbuf, xibuf, zbuf, xdbl, m1_Al, m1_D, ybuf);
  hipLaunchKernelGGL(gemm_res, dim3(256), dim3(256), 0, stream, ybuf, wfold, fo2s, res);
  hipLaunchKernelGGL(colmean, dim3(256), dim3(256), 0, stream, res, fmean);
  hipLaunchKernelGGL(mamba2_kernel, dim3(4), dim3(64), 0, stream,
                     fmean, m2_inw, m2_cw, m2_cb, m2_xp, m2_dtw, m2_dtb, m2_Al, m2_D, m2_ow, fsum);
  hipLaunchKernelGGL(outproj_kernel, dim3(256), dim3(256), 0, stream,
                     res, fsum, opw, opb, x, x2);
  hipLaunchKernelGGL(ln_stats, dim3(4), dim3(256), 0, stream, x2, mu2, rstd2);
  hipLaunchKernelGGL(ffn_in_kernel, dim3(256), dim3(256), 0, stream,
                     x2, n2w, n2b, fiw, fib, mu2, rstd2, gbuf);
  hipLaunchKernelGGL(ffn_dw_gate, dim3(8192), dim3(256), 0, stream, gbuf, fdw, fdb, gmbuf);
  hipLaunchKernelGGL(ffn_out_kernel, dim3(256), dim3(256), 0, stream, gmbuf, fow, fob, x2, out);
}

// Round 3
// 746.970 us; speedup vs baseline: 2.7683x; 1.8306x over previous
//
#include <hip/hip_runtime.h>
#include <math.h>

// OSS / VMamba-style block. B=4, C=64, H=W=64, L=4096, d_inner=512, D_STATE=16.
// All f32. Workspace ~158MB with aliasing.
// R1: m1_scan DPP row-rotate reduce.
// R2: ln_stats -> two-stage reduction (was 2x410us, 4 blocks). m1_scan ->
//     3-pass chunk-parallel scan (8 chunks of 512): pass1 chunk transitions,
//     mid-scan of transitions, pass2 = old scan from hstart with 8x blocks.

#define DEV static __device__ __forceinline__

DEV float silu_f(float x){ return x / (1.f + __expf(-x)); }

// sum across each 16-lane row via DPP row rotations; every lane ends with the sum
DEV float row_sum16(float v){
  v += __int_as_float(__builtin_amdgcn_update_dpp(0, __float_as_int(v), 0x128, 0xF, 0xF, false)); // row_ror:8
  v += __int_as_float(__builtin_amdgcn_update_dpp(0, __float_as_int(v), 0x124, 0xF, 0xF, false)); // row_ror:4
  v += __int_as_float(__builtin_amdgcn_update_dpp(0, __float_as_int(v), 0x122, 0xF, 0xF, false)); // row_ror:2
  v += __int_as_float(__builtin_amdgcn_update_dpp(0, __float_as_int(v), 0x121, 0xF, 0xF, false)); // row_ror:1
  return v;
}

// ---------------- LayerNorm stats, two-stage ----------------
// stage 1: 256 blocks (64 per batch), each reduces 4096 contiguous floats
__global__ __launch_bounds__(256) void ln_part(const float* __restrict__ x,
                                               float2* __restrict__ part){
  int blk = blockIdx.x; int b = blk>>6, pc = blk&63;
  const float* p = x + (size_t)b*262144 + (size_t)pc*4096;
  float s=0.f, s2=0.f;
  #pragma unroll
  for(int it=0; it<4; ++it){
    int i = threadIdx.x + it*256;
    float4 v = *(const float4*)(p + i*4);
    s  += v.x+v.y+v.z+v.w;
    s2 += v.x*v.x+v.y*v.y+v.z*v.z+v.w*v.w;
  }
  __shared__ float ls[256], ls2[256];
  ls[threadIdx.x]=s; ls2[threadIdx.x]=s2; __syncthreads();
  for(int st=128;st>0;st>>=1){
    if(threadIdx.x<st){ ls[threadIdx.x]+=ls[threadIdx.x+st]; ls2[threadIdx.x]+=ls2[threadIdx.x+st]; }
    __syncthreads();
  }
  if(threadIdx.x==0) part[blk]=make_float2(ls[0],ls2[0]);
}
// stage 2: 4 blocks x 64 thr
__global__ __launch_bounds__(64) void ln_fin(const float2* __restrict__ part,
                                             float* __restrict__ mu, float* __restrict__ rstd){
  int b = blockIdx.x;
  float2 v = part[b*64+threadIdx.x];
  __shared__ double ds_[64], ds2_[64];
  ds_[threadIdx.x]=v.x; ds2_[threadIdx.x]=v.y; __syncthreads();
  for(int st=32;st>0;st>>=1){
    if(threadIdx.x<st){ ds_[threadIdx.x]+=ds_[threadIdx.x+st]; ds2_[threadIdx.x]+=ds2_[threadIdx.x+st]; }
    __syncthreads();
  }
  if(threadIdx.x==0){
    double m = ds_[0]*(1.0/262144.0);
    double var = ds2_[0]*(1.0/262144.0) - m*m;
    mu[b]=(float)m; rstd[b]=(float)(1.0/sqrt(var+1e-5));
  }
}

// ---------------- LN1 apply + inproj (64->128) + split, silu on fo2 ----------------
__global__ __launch_bounds__(256) void ln1_inproj(const float* __restrict__ x,
    const float* __restrict__ n1w, const float* __restrict__ n1b,
    const float* __restrict__ ipw, const float* __restrict__ ipb,
    const float* __restrict__ mu, const float* __restrict__ rstd,
    float* __restrict__ fo1_raw, float* __restrict__ fo2s){
  int bh = blockIdx.x; int b = bh>>6, h = bh&63;
  __shared__ float xn[64][64];
  __shared__ float wl[128*64];
  float m = mu[b], rs = rstd[b];
  for(int i=threadIdx.x;i<4096;i+=256){
    int c=i>>6, w=i&63;
    size_t sp=(size_t)c*4096 + h*64 + w;
    float v = x[(size_t)b*262144 + sp];
    xn[c][w] = (v-m)*rs*n1w[sp] + n1b[sp];
  }
  for(int i=threadIdx.x;i<8192;i+=256) wl[i]=ipw[i];
  __syncthreads();
  int px = threadIdx.x & 63, ob = (threadIdx.x>>6)*32;
  float acc[32];
  #pragma unroll
  for(int j=0;j<32;j++) acc[j]=0.f;
  for(int c=0;c<64;c++){
    float xv = xn[c][px];
    #pragma unroll
    for(int j=0;j<32;j++) acc[j] = fmaf(wl[(ob+j)*64+c], xv, acc[j]);
  }
  for(int j=0;j<32;j++){
    int o = ob+j;
    float v = acc[j] + ipb[o];
    if(o<64) fo1_raw[((size_t)(b*64+o))*4096 + h*64 + px] = v;
    else     fo2s  [((size_t)(b*64+o-64))*4096 + h*64 + px] = silu_f(v);
  }
}

// ---------------- depthwise 3x3 + silu, writes normal + transposed spatial ----------------
__global__ __launch_bounds__(256) void dwconv_silu_tr(const float* __restrict__ src_,
    const float* __restrict__ dww, const float* __restrict__ dwb,
    float* __restrict__ fo1s, float* __restrict__ fo1t){
  int bc = blockIdx.x; int c = bc & 63;
  const float* src = src_ + (size_t)bc*4096;
  float wk[9];
  #pragma unroll
  for(int k=0;k<9;k++) wk[k]=dww[c*9+k];
  float bias = dwb[c];
  __shared__ float tl[64][65];
  for(int i=threadIdx.x;i<4096;i+=256){
    int h=i>>6, w=i&63;
    float acc=bias;
    #pragma unroll
    for(int kh=0;kh<3;kh++){
      int ih=h+kh-1; if(ih<0||ih>63) continue;
      #pragma unroll
      for(int kw=0;kw<3;kw++){
        int iw=w+kw-1; if(iw<0||iw>63) continue;
        acc += wk[kh*3+kw]*src[ih*64+iw];
      }
    }
    tl[h][w] = silu_f(acc);
  }
  __syncthreads();
  float* ps = fo1s + (size_t)bc*4096;
  float* pt = fo1t + (size_t)bc*4096;
  for(int i=threadIdx.x;i<4096;i+=256){
    ps[i] = tl[i>>6][i&63];
    pt[i] = tl[i&63][i>>6];
  }
}

// ---------------- gather u (B,256,L) channel-major ----------------
__global__ __launch_bounds__(256) void gather_u(const float* __restrict__ fo1s,
    const float* __restrict__ fo1t, float* __restrict__ u){
  int e = blockIdx.x*256 + threadIdx.x;     // 4*256*4096
  int l = e & 4095, cc = (e>>12)&255, b = e>>20;
  int part = cc>>6, c = cc&63;
  const float* s = (part<2)? fo1s : fo1t;
  int idx = (part&1)? (4095-l) : l;
  u[e] = s[((size_t)(b*64+c))*4096 + idx];
}

// ---------------- GEMM: xz = u @ in_w^T  (16384 x 1024 x 256) ----------------
__global__ __launch_bounds__(256) void gemm_xz(const float* __restrict__ u,
    const float* __restrict__ in_w, float* __restrict__ xi0, float* __restrict__ z){
  int blk = blockIdx.x; int b = blk>>6, l0 = (blk&63)<<6;
  int o0 = blockIdx.y*64;
  __shared__ __align__(16) float a_t[64][64];
  __shared__ float wch[64][65];
  __shared__ float o_t[64][64];
  int t=threadIdx.x, lq=t>>4, cq=t&15;
  float acc[16];
  #pragma unroll
  for(int j=0;j<16;j++) acc[j]=0.f;
  const float* ub = u + ((size_t)b*256)*4096 + l0;
  for(int kc=0;kc<4;kc++){
    __syncthreads();
    for(int i=t;i<4096;i+=256){ int k=i>>6,l=i&63; a_t[k][l]=ub[(size_t)(kc*64+k)*4096 + l]; }
    for(int i=t;i<4096;i+=256){ int r=i>>6,k=i&63; wch[r][k]=in_w[(o0+r)*256 + kc*64 + k]; }
    __syncthreads();
    for(int k=0;k<64;k++){
      const float4 uv = *(const float4*)&a_t[k][lq<<2];
      float uvf[4]; uvf[0]=uv.x; uvf[1]=uv.y; uvf[2]=uv.z; uvf[3]=uv.w;
      float wv[4];
      #pragma unroll
      for(int j=0;j<4;j++) wv[j]=wch[(cq<<2)+j][k];
      #pragma unroll
      for(int ii=0;ii<4;ii++)
        #pragma unroll
        for(int jj=0;jj<4;jj++)
          acc[ii*4+jj]=fmaf(uvf[ii],wv[jj],acc[ii*4+jj]);
    }
  }
  __syncthreads();
  #pragma unroll
  for(int ii=0;ii<4;ii++)
    #pragma unroll
    for(int jj=0;jj<4;jj++)
      o_t[(cq<<2)+jj][(lq<<2)+ii]=acc[ii*4+jj];
  __syncthreads();
  for(int i=t;i<4096;i+=256){
    int o=i>>6,l=i&63; int og=o0+o;
    float v=o_t[o][l];
    if(og<512) xi0[((size_t)(b*512)+og    )*4096 + l0 + l]=v;
    else       z  [((size_t)(b*512)+og-512)*4096 + l0 + l]=v;
  }
}

// ---------------- causal depthwise conv1d (k=4) + silu, (B,512,L) c-major ----------------
__global__ __launch_bounds__(256) void conv1d_silu(const float* __restrict__ xi0,
    const float* __restrict__ cw, const float* __restrict__ cb, float* __restrict__ xi){
  int e = blockIdx.x*256 + threadIdx.x;   // 4*512*4096
  int l = e & 4095, d = (e>>12)&511;
  float acc = cb[d];
  #pragma unroll
  for(int k=0;k<4;k++){
    int ls = l-3+k;
    if(ls>=0) acc += cw[d*4+k]*xi0[e-3+k];
  }
  xi[e] = silu_f(acc);
}

// ---------------- GEMM: x_dbl = xi @ xproj^T (16384 x 48 x 512), out (B,L,48) ----------------
__global__ __launch_bounds__(256) void gemm_xdbl(const float* __restrict__ xi,
    const float* __restrict__ xpw, float* __restrict__ xdbl){
  int blk=blockIdx.x; int b=blk>>6, l0=(blk&63)<<6;
  __shared__ __align__(16) float a_t[64][64];
  __shared__ float wch[48][65];
  int t=threadIdx.x, lq=t>>4, oq=t&15;
  float acc[12];
  #pragma unroll
  for(int j=0;j<12;j++) acc[j]=0.f;
  for(int kc=0;kc<8;kc++){
    __syncthreads();
    for(int i=t;i<4096;i+=256){ int k=i>>6,l=i&63; a_t[k][l]=xi[((size_t)(b*512)+kc*64+k)*4096 + l0+l]; }
    for(int i=t;i<3072;i+=256){ int r=i>>6,k=i&63; wch[r][k]=xpw[r*512 + kc*64 + k]; }
    __syncthreads();
    for(int k=0;k<64;k++){
      const float4 uv = *(const float4*)&a_t[k][lq<<2];
      float uvf[4]; uvf[0]=uv.x; uvf[1]=uv.y; uvf[2]=uv.z; uvf[3]=uv.w;
      float wv[3];
      #pragma unroll
      for(int j=0;j<3;j++) wv[j]=wch[oq*3+j][k];
      #pragma unroll
      for(int ii=0;ii<4;ii++)
        #pragma unroll
        for(int jj=0;jj<3;jj++)
          acc[ii*3+jj]=fmaf(uvf[ii],wv[jj],acc[ii*3+jj]);
    }
  }
  #pragma unroll
  for(int ii=0;ii<4;ii++)
    #pragma unroll
    for(int jj=0;jj<3;jj++)
      xdbl[((size_t)(b*4096)+l0+(lq<<2)+ii)*48 + oq*3+jj]=acc[ii*3+jj];
}

// ---------------- dt = softplus(xdbl[:, :16] @ dt_w^T + dt_b), out (B,512,L) c-major ----------------
__global__ __launch_bounds__(256) void dtproj(const float* __restrict__ xdbl,
    const float* __restrict__ dtw, const float* __restrict__ dtb, float* __restrict__ dt){
  int blk=blockIdx.x; int b=blk>>6, l0=(blk&63)<<6;
  __shared__ float xl[64][17];
  __shared__ float wl[512][17];
  __shared__ float bl[512];
  for(int i=threadIdx.x;i<1024;i+=256){ int l=i>>4,r=i&15; xl[l][r]=xdbl[((size_t)(b*4096)+l0+l)*48 + r]; }
  for(int i=threadIdx.x;i<8192;i+=256){ int d=i>>4,r=i&15; wl[d][r]=dtw[i]; }
  for(int i=threadIdx.x;i<512;i+=256) bl[i]=dtb[i];
  __syncthreads();
  for(int j=threadIdx.x;j<32768;j+=256){
    int d=j>>6, l=j&63;
    float acc=bl[d];
    #pragma unroll
    for(int r=0;r<16;r++) acc=fmaf(xl[l][r], wl[d][r], acc);
    float sp = (acc>20.f)? acc : log1pf(__expf(acc));
    dt[((size_t)(b*512)+d)*4096 + l0 + l]=sp;
  }
}

// ================= chunk-parallel selective scan (8 chunks of 512) =================
// pass 1: per-chunk transition (P = prod dA, q = end state with h0=0)
__global__ __launch_bounds__(64) void m1_scan_p1(
    const float* __restrict__ dt, const float* __restrict__ xi,
    const float* __restrict__ xdbl, const float* __restrict__ Alog,
    float* __restrict__ Pbuf, float* __restrict__ qbuf){
  int blk=blockIdx.x;                  // (b<<10)|(g<<3)|c
  int c = blk&7, g=(blk>>3)&127, b=blk>>10;
  int lane=threadIdx.x, ds=lane>>4, s=lane&15;
  int d = g*4+ds;
  float A2 = -__expf(Alog[d*16+s]) * 1.44269504088896f;
  const size_t base_dl = ((size_t)b*512 + g*4)*4096;
  const float* xb = xdbl + (size_t)b*4096*48;
  __shared__ __align__(16) float dxl[2][4][136];
  __shared__ __align__(16) float Bl[2][64][20];
  int row = lane>>4, c4 = (lane&15)<<2;
  float4 rdt, rxi, rB[4];
  auto issue=[&](int l0){
    size_t o = base_dl + (size_t)row*4096 + l0 + c4;
    rdt = *(const float4*)(dt + o);
    rxi = *(const float4*)(xi + o);
    #pragma unroll
    for(int q=0;q<4;q++){
      int idx=q*64+lane, r=idx>>2, quad=idx&3;
      rB[q] = *(const float4*)(xb + (size_t)(l0+r)*48 + 16 + quad*4);
    }
  };
  auto store=[&](int buf){
    *(float4*)&dxl[buf][row][2*c4]   = make_float4(rdt.x, rxi.x, rdt.y, rxi.y);
    *(float4*)&dxl[buf][row][2*c4+4] = make_float4(rdt.z, rxi.z, rdt.w, rxi.w);
    #pragma unroll
    for(int q=0;q<4;q++){
      int idx=q*64+lane, r=idx>>2, quad=idx&3;
      *(float4*)&Bl[buf][r][quad*4]=rB[q];
    }
  };
  float P=1.f, qacc=0.f;
  int l0base = c*512;
  issue(l0base); store(0); __syncthreads();
  for(int ck=0;ck<8;ck++){
    int buf=ck&1; bool more=(ck+1)<8;
    if(more) issue(l0base+((ck+1)<<6));
    #pragma unroll 4
    for(int j4=0;j4<16;j4++){
      const float4 a  = *(const float4*)&dxl[buf][ds][8*j4];
      const float4 c2 = *(const float4*)&dxl[buf][ds][8*j4+4];
      {
        float dA=exp2f(a.x*A2);  P*=dA;  qacc=fmaf(dA,qacc,a.x*a.y*Bl[buf][4*j4+0][s]);
      }{
        float dA=exp2f(a.z*A2);  P*=dA;  qacc=fmaf(dA,qacc,a.z*a.w*Bl[buf][4*j4+1][s]);
      }{
        float dA=exp2f(c2.x*A2); P*=dA;  qacc=fmaf(dA,qacc,c2.x*c2.y*Bl[buf][4*j4+2][s]);
      }{
        float dA=exp2f(c2.z*A2); P*=dA;  qacc=fmaf(dA,qacc,c2.z*c2.w*Bl[buf][4*j4+3][s]);
      }
    }
    __syncthreads();
    if(more){ store(buf^1); __syncthreads(); }
  }
  size_t oidx = (((size_t)(b*128+g))*8+c)*64 + lane;
  Pbuf[oidx]=P; qbuf[oidx]=qacc;
}

// middle: scan the 8 chunk transitions per (b,g,lane) -> hstart per chunk
__global__ __launch_bounds__(256) void m1_scan_mid(
    const float* __restrict__ Pbuf, const float* __restrict__ qbuf,
    float* __restrict__ hstart){
  int tid = blockIdx.x*256 + threadIdx.x;   // 32768 = 512 groups * 64 lanes
  int lane = tid&63, bg = tid>>6;
  size_t base = (size_t)bg*8*64 + lane;
  float h=0.f;
  #pragma unroll
  for(int c=0;c<8;c++){
    size_t idx = base + (size_t)c*64;
    hstart[idx]=h;
    h = fmaf(Pbuf[idx], h, qbuf[idx]);
  }
}

// pass 2: full scan within chunk starting from hstart; emits gated y
__global__ __launch_bounds__(64) void m1_scan_p2(
    const float* __restrict__ dt, const float* __restrict__ xi, const float* __restrict__ z,
    const float* __restrict__ xdbl, const float* __restrict__ Alog, const float* __restrict__ Dp,
    const float* __restrict__ hstart, float* __restrict__ y){
  int blk=blockIdx.x;                  // (b<<10)|(g<<3)|c
  int c = blk&7, g=(blk>>3)&127, b=blk>>10;
  int dbase = g*4;
  int lane = threadIdx.x;
  int ds = lane>>4, s = lane&15;
  int d = dbase + ds;
  float A2 = -__expf(Alog[d*16+s]) * 1.44269504088896f;
  float D4[4];
  #pragma unroll
  for(int dd=0;dd<4;dd++) D4[dd]=Dp[dbase+dd];
  const size_t base_dl = ((size_t)b*512 + dbase)*4096;
  const float* xb = xdbl + (size_t)b*4096*48;

  __shared__ __align__(16) float  dxl[2][4][136];
  __shared__ __align__(16) float  zl [2][4][68];
  __shared__ __align__(16) float4 bcl4[2][64][9];
  __shared__ __align__(16) float4 pl4[16][4];

  int row = lane>>4, c4 = (lane&15)<<2;
  float4 rdt, rxi, rz;
  float2 rb[8], rc[8];

  auto issue_loads=[&](int l0){
    size_t o = base_dl + (size_t)row*4096 + l0 + c4;
    rdt = *(const float4*)(dt + o);
    rxi = *(const float4*)(xi + o);
    rz  = *(const float4*)(z  + o);
    #pragma unroll
    for(int q=0;q<8;q++){
      int r = q*8 + (lane>>3), s2 = (lane&7)*2;
      const float* rowp = xb + (size_t)(l0+r)*48;
      rb[q] = *(const float2*)(rowp + 16 + s2);
      rc[q] = *(const float2*)(rowp + 32 + s2);
    }
  };
  auto store_lds=[&](int buf){
    *(float4*)&dxl[buf][row][2*c4]   = make_float4(rdt.x, rxi.x, rdt.y, rxi.y);
    *(float4*)&dxl[buf][row][2*c4+4] = make_float4(rdt.z, rxi.z, rdt.w, rxi.w);
    *(float4*)&zl[buf][row][c4]      = rz;
    #pragma unroll
    for(int q=0;q<8;q++){
      int r = q*8 + (lane>>3), s2h = lane&7;
      bcl4[buf][r][s2h] = make_float4(rb[q].x, rc[q].x, rb[q].y, rc[q].y);
    }
  };

  float h = hstart[(((size_t)(b*128+g))*8+c)*64 + lane];
  int lbase = c*512;
  issue_loads(lbase); store_lds(0); __syncthreads();
  for(int ck=0;ck<8;ck++){
    int buf = ck&1;
    bool more = (ck+1)<8;
    if(more) issue_loads(lbase+((ck+1)<<6));
    const char* bcbase = (const char*)&bcl4[buf][0][s>>1] + (s&1)*8;
    #pragma unroll 4
    for(int j4=0;j4<16;j4++){
      const float4 a  = *(const float4*)&dxl[buf][ds][8*j4];
      const float4 c2 = *(const float4*)&dxl[buf][ds][8*j4+4];
      float4 pacc;
      {
        float2 bc = *(const float2*)(bcbase + (size_t)(4*j4+0)*144);
        float dA = exp2f(a.x*A2);
        h = fmaf(dA, h, a.x*a.y*bc.x);
        pacc.x = row_sum16(h*bc.y);
      }
      {
        float2 bc = *(const float2*)(bcbase + (size_t)(4*j4+1)*144);
        float dA = exp2f(a.z*A2);
        h = fmaf(dA, h, a.z*a.w*bc.x);
        pacc.y = row_sum16(h*bc.y);
      }
      {
        float2 bc = *(const float2*)(bcbase + (size_t)(4*j4+2)*144);
        float dA = exp2f(c2.x*A2);
        h = fmaf(dA, h, c2.x*c2.y*bc.x);
        pacc.z = row_sum16(h*bc.y);
      }
      {
        float2 bc = *(const float2*)(bcbase + (size_t)(4*j4+3)*144);
        float dA = exp2f(c2.z*A2);
        h = fmaf(dA, h, c2.z*c2.w*bc.x);
        pacc.w = row_sum16(h*bc.y);
      }
      if(s==15) pl4[j4][ds] = pacc;
    }
    __syncthreads();
    int l0 = lbase + (ck<<6);
    int t = lane;
    #pragma unroll
    for(int dd=0;dd<4;dd++){
      float ps  = ((const float*)&pl4[t>>2][dd])[t&3];
      float xiv = dxl[buf][dd][2*t+1];
      float zv  = zl[buf][dd][t];
      y[base_dl + (size_t)dd*4096 + l0 + t] = (ps + xiv*D4[dd]) * silu_f(zv);
    }
    if(more) store_lds(buf^1);
    __syncthreads();
  }
}

// ---------------- fold out_w over the 4 direction groups: W'(64,512) ----------------
__global__ __launch_bounds__(256) void fold_w(const float* __restrict__ ow, float* __restrict__ wf){
  int i = blockIdx.x*256 + threadIdx.x;   // 32768
  if(i>=32768) return;
  int c = i>>9, d2 = i&511;
  wf[i] = ow[(c)*512+d2] + ow[(64+c)*512+d2] + ow[(128+c)*512+d2] + ow[(192+c)*512+d2];
}

// ---------------- GEMM: res = (y @ W'^T) * fo2s ; y (B,512,L), out res (B,64,L) ----------------
__global__ __launch_bounds__(256) void gemm_res(const float* __restrict__ y,
    const float* __restrict__ wf, const float* __restrict__ fo2s, float* __restrict__ res){
  int blk=blockIdx.x; int b=blk>>6, l0=(blk&63)<<6;
  __shared__ __align__(16) float a_t[64][64];
  __shared__ float wch[64][65];
  __shared__ float o_t[64][64];
  int t=threadIdx.x, lq=t>>4, cq=t&15;
  float acc[16];
  #pragma unroll
  for(int j=0;j<16;j++) acc[j]=0.f;
  for(int kc=0;kc<8;kc++){
    __syncthreads();
    for(int i=t;i<4096;i+=256){ int k=i>>6,l=i&63; a_t[k][l]=y[((size_t)(b*512)+kc*64+k)*4096 + l0+l]; }
    for(int i=t;i<4096;i+=256){ int r=i>>6,k=i&63; wch[r][k]=wf[r*512 + kc*64 + k]; }
    __syncthreads();
    for(int k=0;k<64;k++){
      const float4 uv = *(const float4*)&a_t[k][lq<<2];
      float uvf[4]; uvf[0]=uv.x; uvf[1]=uv.y; uvf[2]=uv.z; uvf[3]=uv.w;
      float wv[4];
      #pragma unroll
      for(int j=0;j<4;j++) wv[j]=wch[(cq<<2)+j][k];
      #pragma unroll
      for(int ii=0;ii<4;ii++)
        #pragma unroll
        for(int jj=0;jj<4;jj++)
          acc[ii*4+jj]=fmaf(uvf[ii],wv[jj],acc[ii*4+jj]);
    }
  }
  __syncthreads();
  #pragma unroll
  for(int ii=0;ii<4;ii++)
    #pragma unroll
    for(int jj=0;jj<4;jj++)
      o_t[(cq<<2)+jj][(lq<<2)+ii]=acc[ii*4+jj];
  __syncthreads();
  for(int i=t;i<4096;i+=256){
    int o=i>>6,l=i&63;
    size_t idx=((size_t)(b*64+o))*4096 + l0 + l;
    res[idx]=o_t[o][l]*fo2s[idx];
  }
}

// ---------------- per (b,c) spatial mean ----------------
__global__ __launch_bounds__(256) void colmean(const float* __restrict__ res, float* __restrict__ fm){
  int bc = blockIdx.x;
  const float* p = res + (size_t)bc*4096;
  float s=0;
  for(int i=threadIdx.x;i<4096;i+=256) s+=p[i];
  __shared__ float ls[256];
  ls[threadIdx.x]=s; __syncthreads();
  for(int st=128;st>0;st>>=1){ if(threadIdx.x<st) ls[threadIdx.x]+=ls[threadIdx.x+st]; __syncthreads(); }
  if(threadIdx.x==0) fm[bc]=ls[0]*(1.f/4096.f);
}

// ---------------- tiny mamba2 over channel sequence (L=64, d_model=2, d_inner=4) ----------------
__global__ __launch_bounds__(64) void mamba2_kernel(const float* __restrict__ fm,
    const float* __restrict__ in_w, const float* __restrict__ cw, const float* __restrict__ cb,
    const float* __restrict__ xp, const float* __restrict__ dtw, const float* __restrict__ dtb,
    const float* __restrict__ Alog, const float* __restrict__ Dp, const float* __restrict__ ow,
    float* __restrict__ fsum){
  int b = blockIdx.x; int t = threadIdx.x;   // 0..63
  __shared__ float xi0m[64][4], xim[64][4], dtm[64][4], xbl[64][33], ym[64][4];
  float a0 = fm[b*64+t], a1 = fm[b*64 + 63-t];
  float zreg[4];
  #pragma unroll
  for(int d2=0;d2<4;d2++){
    xi0m[t][d2] = in_w[d2*2+0]*a0 + in_w[d2*2+1]*a1;
    zreg[d2]    = in_w[(4+d2)*2+0]*a0 + in_w[(4+d2)*2+1]*a1;
  }
  __syncthreads();
  float xir[4];
  #pragma unroll
  for(int d2=0;d2<4;d2++){
    float acc=cb[d2];
    #pragma unroll
    for(int k=0;k<4;k++){
      int srow=t-3+k;
      if(srow>=0) acc += cw[d2*4+k]*xi0m[srow][d2];
    }
    xir[d2]=silu_f(acc);
    xim[t][d2]=xir[d2];
  }
  for(int j=0;j<33;j++){
    float acc=0;
    #pragma unroll
    for(int d2=0;d2<4;d2++) acc += xp[j*4+d2]*xir[d2];
    xbl[t][j]=acc;
  }
  #pragma unroll
  for(int d2=0;d2<4;d2++){
    float v = xbl[t][0]*dtw[d2] + dtb[d2];
    dtm[t][d2] = (v>20.f)? v : log1pf(__expf(v));
  }
  __syncthreads();
  int dd=t>>4, s=t&15;
  float A2 = -__expf(Alog[dd*16+s]) * 1.44269504088896f;
  float h=0.f;
  for(int c=0;c<64;c++){
    float dtv=dtm[c][dd];
    float dA=exp2f(dtv*A2);
    h = fmaf(dA, h, dtv*xim[c][dd]*xbl[c][1+s]);
    float p = h*xbl[c][17+s];
    p += __shfl_xor(p,1,16);
    p += __shfl_xor(p,2,16);
    p += __shfl_xor(p,4,16);
    p += __shfl_xor(p,8,16);
    if(s==0) ym[c][dd]=p;
  }
  __syncthreads();
  float os=0.f;
  #pragma unroll
  for(int d2=0;d2<4;d2++){
    float yv = (ym[t][d2] + xim[t][d2]*Dp[d2]) * silu_f(zreg[d2]);
    os += yv * (ow[d2] + ow[4+d2]);
  }
  fsum[b*64+t]=os;
}

// ---------------- foss = res*(1+foc) ; x2 = outproj(foss) + x ----------------
__global__ __launch_bounds__(256) void outproj_kernel(const float* __restrict__ res,
    const float* __restrict__ fsum, const float* __restrict__ opw, const float* __restrict__ opb,
    const float* __restrict__ x, float* __restrict__ x2){
  int bh=blockIdx.x; int b=bh>>6,h=bh&63;
  __shared__ float tile[64][64];
  __shared__ float wl[4096];
  for(int i=threadIdx.x;i<4096;i+=256) wl[i]=opw[i];
  for(int i=threadIdx.x;i<4096;i+=256){
    int c=i>>6,w=i&63;
    tile[c][w]=res[((size_t)(b*64+c))*4096 + h*64 + w]*(1.f+fsum[b*64+c]);
  }
  __syncthreads();
  int px=threadIdx.x&63, og=threadIdx.x>>6;
  float acc[16];
  #pragma unroll
  for(int j=0;j<16;j++) acc[j]=0.f;
  for(int c=0;c<64;c++){
    float v=tile[c][px];
    #pragma unroll
    for(int j=0;j<16;j++) acc[j]=fmaf(wl[(og*16+j)*64+c],v,acc[j]);
  }
  for(int j=0;j<16;j++){
    int o=og*16+j;
    size_t idx=((size_t)(b*64+o))*4096 + h*64 + px;
    x2[idx]=acc[j]+opb[o]+x[idx];
  }
}

// ---------------- LN2 apply + ffn_in (64->256) ----------------
__global__ __launch_bounds__(256) void ffn_in_kernel(const float* __restrict__ x2,
    const float* __restrict__ n2w, const float* __restrict__ n2b,
    const float* __restrict__ fiw, const float* __restrict__ fib,
    const float* __restrict__ mu2, const float* __restrict__ rstd2,
    float* __restrict__ g){
  int bh=blockIdx.x; int b=bh>>6,h=bh&63;
  __shared__ float tile[64][64];
  __shared__ float wl[256*64];
  float m=mu2[b], rs=rstd2[b];
  for(int i=threadIdx.x;i<4096;i+=256){
    int c=i>>6,w=i&63;
    size_t sp=(size_t)c*4096 + h*64 + w;
    tile[c][w]=(x2[(size_t)b*262144+sp]-m)*rs*n2w[sp]+n2b[sp];
  }
  for(int i=threadIdx.x;i<16384;i+=256) wl[i]=fiw[i];
  __syncthreads();
  int px=threadIdx.x&63, og=threadIdx.x>>6;
  for(int half=0;half<2;half++){
    float acc[32];
    #pragma unroll
    for(int j=0;j<32;j++) acc[j]=0.f;
    int ob = half*128 + og*32;
    for(int c=0;c<64;c++){
      float v=tile[c][px];
      #pragma unroll
      for(int j=0;j<32;j++) acc[j]=fmaf(wl[(ob+j)*64+c],v,acc[j]);
    }
    for(int j=0;j<32;j++){
      int o=ob+j;
      g[((size_t)(b*256+o))*4096 + h*64 + px]=acc[j]+fib[o];
    }
  }
}

// ---------------- ffn depthwise 3x3 + gelu-gate ----------------
__global__ __launch_bounds__(256) void ffn_dw_gate(const float* __restrict__ g,
    const float* __restrict__ dww, const float* __restrict__ dwb, float* __restrict__ gm){
  int e = blockIdx.x*256 + threadIdx.x;   // 4*128*4096
  int sp = e & 4095, j = (e>>12)&127, b = e>>19;
  int h = sp>>6, w = sp&63;
  float v[2];
  #pragma unroll
  for(int half=0;half<2;half++){
    int ch = j + half*128;
    const float* gp = g + ((size_t)(b*256+ch))*4096;
    float acc = dwb[ch];
    #pragma unroll
    for(int kh=0;kh<3;kh++){
      int ih=h+kh-1; if(ih<0||ih>63) continue;
      #pragma unroll
      for(int kw=0;kw<3;kw++){
        int iw=w+kw-1; if(iw<0||iw>63) continue;
        acc += dww[ch*9+kh*3+kw]*gp[ih*64+iw];
      }
    }
    v[half]=acc;
  }
  float ge = 0.5f*v[0]*(1.f+erff(v[0]*0.70710678f));
  gm[((size_t)(b*128+j))*4096 + sp] = ge*v[1];
}

// ---------------- ffn_out (128->64) + bias + residual add -> d_out ----------------
__global__ __launch_bounds__(256) void ffn_out_kernel(const float* __restrict__ gm,
    const float* __restrict__ fow, const float* __restrict__ fob,
    const float* __restrict__ x2, float* __restrict__ out){
  int bh=blockIdx.x; int b=bh>>6,h=bh&63;
  __shared__ float tile[128][64];
  __shared__ float wl[64*128];
  for(int i=threadIdx.x;i<8192;i+=256){
    int c=i>>6,w=i&63;
    tile[c][w]=gm[((size_t)(b*128+c))*4096 + h*64 + w];
  }
  for(int i=threadIdx.x;i<8192;i+=256) wl[i]=fow[i];
  __syncthreads();
  int px=threadIdx.x&63, og=threadIdx.x>>6;
  float acc[16];
  #pragma unroll
  for(int j=0;j<16;j++) acc[j]=0.f;
  for(int c=0;c<128;c++){
    float v=tile[c][px];
    #pragma unroll
    for(int j=0;j<16;j++) acc[j]=fmaf(wl[(og*16+j)*128+c],v,acc[j]);
  }
  for(int j=0;j<16;j++){
    int o=og*16+j;
    size_t idx=((size_t)(b*64+o))*4096 + h*64 + px;
    out[idx]=acc[j]+fob[o]+x2[idx];
  }
}

extern "C" void kernel_launch(void* const* d_in, const int* in_sizes, int n_in,
                              void* d_out, int out_size, void* d_ws, size_t ws_size,
                              hipStream_t stream){
  const float* x      = (const float*)d_in[0];
  const float* n1w    = (const float*)d_in[1];
  const float* n1b    = (const float*)d_in[2];
  const float* n2w    = (const float*)d_in[3];
  const float* n2b    = (const float*)d_in[4];
  const float* ipw    = (const float*)d_in[5];
  const float* ipb    = (const float*)d_in[6];
  const float* dww    = (const float*)d_in[7];
  const float* dwb    = (const float*)d_in[8];
  const float* opw    = (const float*)d_in[9];
  const float* opb    = (const float*)d_in[10];
  const float* m1_inw = (const float*)d_in[11];
  const float* m1_cw  = (const float*)d_in[12];
  const float* m1_cb  = (const float*)d_in[13];
  const float* m1_xp  = (const float*)d_in[14];
  const float* m1_dtw = (const float*)d_in[15];
  const float* m1_dtb = (const float*)d_in[16];
  const float* m1_Al  = (const float*)d_in[17];
  const float* m1_D   = (const float*)d_in[18];
  const float* m1_ow  = (const float*)d_in[19];
  const float* m2_inw = (const float*)d_in[20];
  const float* m2_cw  = (const float*)d_in[21];
  const float* m2_cb  = (const float*)d_in[22];
  const float* m2_xp  = (const float*)d_in[23];
  const float* m2_dtw = (const float*)d_in[24];
  const float* m2_dtb = (const float*)d_in[25];
  const float* m2_Al  = (const float*)d_in[26];
  const float* m2_D   = (const float*)d_in[27];
  const float* m2_ow  = (const float*)d_in[28];
  const float* fiw    = (const float*)d_in[29];
  const float* fib    = (const float*)d_in[30];
  const float* fdw    = (const float*)d_in[31];
  const float* fdb    = (const float*)d_in[32];
  const float* fow    = (const float*)d_in[33];
  const float* fob    = (const float*)d_in[34];
  float* out = (float*)d_out;
  float* ws  = (float*)d_ws;

  // workspace layout (floats), aliased.
  float* mu1   = ws + 0;  float* rstd1 = ws + 4;
  float* mu2   = ws + 8;  float* rstd2 = ws + 12;
  float* fmean = ws + 64;    // 256
  float* fsum  = ws + 320;   // 256
  float* wfold = ws + 1024;  // 32768
  float* lnpart= ws + 33792; // 512 floats (256 float2)
  float* fo1raw= ws + 36864;           // 1M   (later: res)
  float* fo2s  = fo1raw + 1048576;     // 1M
  float* fo1s  = fo2s   + 1048576;     // 1M  (later: Pbuf/qbuf/hstart for scan)
  float* fo1t  = fo1s   + 1048576;     // 1M
  float* ubuf  = fo1t   + 1048576;     // (u; later dt 8M; later g 4M)
  float* dtbuf = ubuf;                 // (B,512,L)
  float* gbuf  = ubuf;                 // (B,256,L)
  float* xi0   = ubuf + 8388608;       // 8M  (later: y)
  float* ybuf  = xi0;
  float* zbuf  = xi0  + 8388608;       // 8M  (later: gm 2M)
  float* gmbuf = zbuf;
  float* xibuf = zbuf + 8388608;       // 8M
  float* xdbl  = xibuf+ 8388608;       // 786432
  float* x2    = xdbl + 786432;        // 1M
  float* res   = fo1raw;
  // scan chunk buffers alias fo1s (free after gather_u): 3 x 262144 floats
  float* Pbuf   = fo1s;
  float* qbuf   = fo1s + 262144;
  float* hstart = fo1s + 524288;

  hipLaunchKernelGGL(ln_part, dim3(256), dim3(256), 0, stream, x, (float2*)lnpart);
  hipLaunchKernelGGL(ln_fin, dim3(4), dim3(64), 0, stream, (const float2*)lnpart, mu1, rstd1);
  hipLaunchKernelGGL(ln1_inproj, dim3(256), dim3(256), 0, stream,
                     x, n1w, n1b, ipw, ipb, mu1, rstd1, fo1raw, fo2s);
  hipLaunchKernelGGL(dwconv_silu_tr, dim3(256), dim3(256), 0, stream,
                     fo1raw, dww, dwb, fo1s, fo1t);
  hipLaunchKernelGGL(gather_u, dim3(16384), dim3(256), 0, stream, fo1s, fo1t, ubuf);
  hipLaunchKernelGGL(gemm_xz, dim3(256,16), dim3(256), 0, stream, ubuf, m1_inw, xi0, zbuf);
  hipLaunchKernelGGL(conv1d_silu, dim3(32768), dim3(256), 0, stream, xi0, m1_cw, m1_cb, xibuf);
  hipLaunchKernelGGL(gemm_xdbl, dim3(256), dim3(256), 0, stream, xibuf, m1_xp, xdbl);
  hipLaunchKernelGGL(dtproj, dim3(256), dim3(256), 0, stream, xdbl, m1_dtw, m1_dtb, dtbuf);
  hipLaunchKernelGGL(fold_w, dim3(128), dim3(256), 0, stream, m1_ow, wfold);
  hipLaunchKernelGGL(m1_scan_p1, dim3(4096), dim3(64), 0, stream,
                     dtbuf, xibuf, xdbl, m1_Al, Pbuf, qbuf);
  hipLaunchKernelGGL(m1_scan_mid, dim3(128), dim3(256), 0, stream, Pbuf, qbuf, hstart);
  hipLaunchKernelGGL(m1_scan_p2, dim3(4096), dim3(64), 0, stream,
                     dtbuf, xibuf, zbuf, xdbl, m1_Al, m1_D, hstart, ybuf);
  hipLaunchKernelGGL(gemm_res, dim3(256), dim3(256), 0, stream, ybuf, wfold, fo2s, res);
  hipLaunchKernelGGL(colmean, dim3(256), dim3(256), 0, stream, res, fmean);
  hipLaunchKernelGGL(mamba2_kernel, dim3(4), dim3(64), 0, stream,
                     fmean, m2_inw, m2_cw, m2_cb, m2_xp, m2_dtw, m2_dtb, m2_Al, m2_D, m2_ow, fsum);
  hipLaunchKernelGGL(outproj_kernel, dim3(256), dim3(256), 0, stream,
                     res, fsum, opw, opb, x, x2);
  hipLaunchKernelGGL(ln_part, dim3(256), dim3(256), 0, stream, x2, (float2*)lnpart);
  hipLaunchKernelGGL(ln_fin, dim3(4), dim3(64), 0, stream, (const float2*)lnpart, mu2, rstd2);
  hipLaunchKernelGGL(ffn_in_kernel, dim3(256), dim3(256), 0, stream,
                     x2, n2w, n2b, fiw, fib, mu2, rstd2, gbuf);
  hipLaunchKernelGGL(ffn_dw_gate, dim3(8192), dim3(256), 0, stream, gbuf, fdw, fdb, gmbuf);
  hipLaunchKernelGGL(ffn_out_kernel, dim3(256), dim3(256), 0, stream, gmbuf, fow, fob, x2, out);
}

// Round 4
// 555.512 us; speedup vs baseline: 3.7224x; 1.3447x over previous
//
#include <hip/hip_runtime.h>
#include <math.h>

// OSS / VMamba-style block. B=4, C=64, H=W=64, L=4096, d_inner=512, D_STATE=16.
// R1: m1_scan DPP row-rotate reduce.
// R2: two-stage LN stats; chunk-parallel scan (8 chunks).
// R3: gemm_xz -> bf16 MFMA (16x16x32), u gathered transposed (B,L,256) bf16.

#define DEV static __device__ __forceinline__

DEV float silu_f(float x){ return x / (1.f + __expf(-x)); }

DEV ushort f2bf(float f){
  uint u = __float_as_uint(f);
  uint r = (u + 0x7FFF + ((u>>16)&1)) >> 16;
  return (ushort)r;
}
DEV uint f2bf2(float lo, float hi){
  return (uint)f2bf(lo) | ((uint)f2bf(hi)<<16);
}

typedef __attribute__((ext_vector_type(8))) short bf8_t;
typedef __attribute__((ext_vector_type(4))) float f4_t;

// sum across each 16-lane row via DPP row rotations; every lane ends with the sum
DEV float row_sum16(float v){
  v += __int_as_float(__builtin_amdgcn_update_dpp(0, __float_as_int(v), 0x128, 0xF, 0xF, false)); // row_ror:8
  v += __int_as_float(__builtin_amdgcn_update_dpp(0, __float_as_int(v), 0x124, 0xF, 0xF, false)); // row_ror:4
  v += __int_as_float(__builtin_amdgcn_update_dpp(0, __float_as_int(v), 0x122, 0xF, 0xF, false)); // row_ror:2
  v += __int_as_float(__builtin_amdgcn_update_dpp(0, __float_as_int(v), 0x121, 0xF, 0xF, false)); // row_ror:1
  return v;
}

// ---------------- LayerNorm stats, two-stage ----------------
__global__ __launch_bounds__(256) void ln_part(const float* __restrict__ x,
                                               float2* __restrict__ part){
  int blk = blockIdx.x; int b = blk>>6, pc = blk&63;
  const float* p = x + (size_t)b*262144 + (size_t)pc*4096;
  float s=0.f, s2=0.f;
  #pragma unroll
  for(int it=0; it<4; ++it){
    int i = threadIdx.x + it*256;
    float4 v = *(const float4*)(p + i*4);
    s  += v.x+v.y+v.z+v.w;
    s2 += v.x*v.x+v.y*v.y+v.z*v.z+v.w*v.w;
  }
  __shared__ float ls[256], ls2[256];
  ls[threadIdx.x]=s; ls2[threadIdx.x]=s2; __syncthreads();
  for(int st=128;st>0;st>>=1){
    if(threadIdx.x<st){ ls[threadIdx.x]+=ls[threadIdx.x+st]; ls2[threadIdx.x]+=ls2[threadIdx.x+st]; }
    __syncthreads();
  }
  if(threadIdx.x==0) part[blk]=make_float2(ls[0],ls2[0]);
}
__global__ __launch_bounds__(64) void ln_fin(const float2* __restrict__ part,
                                             float* __restrict__ mu, float* __restrict__ rstd){
  int b = blockIdx.x;
  float2 v = part[b*64+threadIdx.x];
  __shared__ double ds_[64], ds2_[64];
  ds_[threadIdx.x]=v.x; ds2_[threadIdx.x]=v.y; __syncthreads();
  for(int st=32;st>0;st>>=1){
    if(threadIdx.x<st){ ds_[threadIdx.x]+=ds_[threadIdx.x+st]; ds2_[threadIdx.x]+=ds2_[threadIdx.x+st]; }
    __syncthreads();
  }
  if(threadIdx.x==0){
    double m = ds_[0]*(1.0/262144.0);
    double var = ds2_[0]*(1.0/262144.0) - m*m;
    mu[b]=(float)m; rstd[b]=(float)(1.0/sqrt(var+1e-5));
  }
}

// ---------------- LN1 apply + inproj (64->128) + split, silu on fo2 ----------------
__global__ __launch_bounds__(256) void ln1_inproj(const float* __restrict__ x,
    const float* __restrict__ n1w, const float* __restrict__ n1b,
    const float* __restrict__ ipw, const float* __restrict__ ipb,
    const float* __restrict__ mu, const float* __restrict__ rstd,
    float* __restrict__ fo1_raw, float* __restrict__ fo2s){
  int bh = blockIdx.x; int b = bh>>6, h = bh&63;
  __shared__ float xn[64][64];
  __shared__ float wl[128*64];
  float m = mu[b], rs = rstd[b];
  for(int i=threadIdx.x;i<4096;i+=256){
    int c=i>>6, w=i&63;
    size_t sp=(size_t)c*4096 + h*64 + w;
    float v = x[(size_t)b*262144 + sp];
    xn[c][w] = (v-m)*rs*n1w[sp] + n1b[sp];
  }
  for(int i=threadIdx.x;i<8192;i+=256) wl[i]=ipw[i];
  __syncthreads();
  int px = threadIdx.x & 63, ob = (threadIdx.x>>6)*32;
  float acc[32];
  #pragma unroll
  for(int j=0;j<32;j++) acc[j]=0.f;
  for(int c=0;c<64;c++){
    float xv = xn[c][px];
    #pragma unroll
    for(int j=0;j<32;j++) acc[j] = fmaf(wl[(ob+j)*64+c], xv, acc[j]);
  }
  for(int j=0;j<32;j++){
    int o = ob+j;
    float v = acc[j] + ipb[o];
    if(o<64) fo1_raw[((size_t)(b*64+o))*4096 + h*64 + px] = v;
    else     fo2s  [((size_t)(b*64+o-64))*4096 + h*64 + px] = silu_f(v);
  }
}

// ---------------- depthwise 3x3 + silu, writes normal + transposed spatial ----------------
__global__ __launch_bounds__(256) void dwconv_silu_tr(const float* __restrict__ src_,
    const float* __restrict__ dww, const float* __restrict__ dwb,
    float* __restrict__ fo1s, float* __restrict__ fo1t){
  int bc = blockIdx.x; int c = bc & 63;
  const float* src = src_ + (size_t)bc*4096;
  float wk[9];
  #pragma unroll
  for(int k=0;k<9;k++) wk[k]=dww[c*9+k];
  float bias = dwb[c];
  __shared__ float tl[64][65];
  for(int i=threadIdx.x;i<4096;i+=256){
    int h=i>>6, w=i&63;
    float acc=bias;
    #pragma unroll
    for(int kh=0;kh<3;kh++){
      int ih=h+kh-1; if(ih<0||ih>63) continue;
      #pragma unroll
      for(int kw=0;kw<3;kw++){
        int iw=w+kw-1; if(iw<0||iw>63) continue;
        acc += wk[kh*3+kw]*src[ih*64+iw];
      }
    }
    tl[h][w] = silu_f(acc);
  }
  __syncthreads();
  float* ps = fo1s + (size_t)bc*4096;
  float* pt = fo1t + (size_t)bc*4096;
  for(int i=threadIdx.x;i<4096;i+=256){
    ps[i] = tl[i>>6][i&63];
    pt[i] = tl[i&63][i>>6];
  }
}

// ---------------- convert in_w to bf16 ----------------
__global__ __launch_bounds__(256) void cvt_w_bf(const float* __restrict__ w, uint* __restrict__ wb){
  int i = blockIdx.x*256 + threadIdx.x;   // 131072 pairs
  float2 v = *(const float2*)(w + 2*i);
  wb[i] = f2bf2(v.x, v.y);
}

// ---------------- gather u transposed: (B, L=4096, 256) bf16 ----------------
__global__ __launch_bounds__(256) void gather_u_t(const float* __restrict__ fo1s,
    const float* __restrict__ fo1t, uint* __restrict__ u_bf){
  int blk = blockIdx.x;             // ((b*4+part)<<6)|lt
  int lt = blk&63, part = (blk>>6)&3, b = blk>>8;
  int l0 = lt<<6;
  const float* s = (part<2)? fo1s : fo1t;
  bool rev = part&1;
  __shared__ float tl[64][65];
  for(int i=threadIdx.x;i<4096;i+=256){
    int c=i>>6, j=i&63;
    int l = l0 + j;
    int idx = rev ? (4095-l) : l;
    tl[c][j] = s[((size_t)(b*64+c))*4096 + idx];
  }
  __syncthreads();
  for(int i=threadIdx.x;i<2048;i+=256){
    int j = i>>5, cp = i&31;
    int l = l0 + j;
    u_bf[((size_t)(b*4096)+l)*128 + part*32 + cp] = f2bf2(tl[2*cp][j], tl[2*cp+1][j]);
  }
}

// ---------------- MFMA GEMM: xz = W(1024,256) x U^T ; U_t (B,4096,256) bf16 ----------------
// grid: x = b*32 + ltile(128), y = otile(128). 256 thr = 4 waves (2x2 of 64x64).
__global__ __launch_bounds__(256) void gemm_xz_mfma(const ushort* __restrict__ u_bf,
    const ushort* __restrict__ w_bf, float* __restrict__ xi0, float* __restrict__ z){
  int blk = blockIdx.x; int b = blk>>5; int l0 = (blk&31)<<7;
  int o0 = blockIdx.y<<7;
  __shared__ ushort Al[2][5120];   // 128 rows x 32 k, stride 40
  __shared__ ushort Bl[2][5120];
  int t = threadIdx.x, lane = t&63, wid = t>>6;
  int wr = wid>>1, wc = wid&1;
  int rl = lane&15, kseg = (lane>>4)*8;
  f4_t acc[4][4];
  #pragma unroll
  for(int m=0;m<4;m++)
    #pragma unroll
    for(int n=0;n<4;n++) acc[m][n]=(f4_t){0.f,0.f,0.f,0.f};

  int r0 = t>>2, r1 = 64+(t>>2), seg = t&3;
  uint4 rA0,rA1,rB0,rB1;
  auto issue=[&](int kc){
    rA0 = *(const uint4*)&w_bf[(size_t)(o0+r0)*256 + kc*32 + seg*8];
    rA1 = *(const uint4*)&w_bf[(size_t)(o0+r1)*256 + kc*32 + seg*8];
    rB0 = *(const uint4*)&u_bf[((size_t)(b*4096)+l0+r0)*256 + kc*32 + seg*8];
    rB1 = *(const uint4*)&u_bf[((size_t)(b*4096)+l0+r1)*256 + kc*32 + seg*8];
  };
  auto store=[&](int buf){
    *(uint4*)&Al[buf][r0*40 + seg*8] = rA0;
    *(uint4*)&Al[buf][r1*40 + seg*8] = rA1;
    *(uint4*)&Bl[buf][r0*40 + seg*8] = rB0;
    *(uint4*)&Bl[buf][r1*40 + seg*8] = rB1;
  };
  issue(0); store(0); __syncthreads();
  int buf=0;
  for(int kc=0;kc<8;kc++){
    bool more = kc<7;
    if(more) issue(kc+1);
    bf8_t af[4], bfr[4];
    #pragma unroll
    for(int m=0;m<4;m++) af[m] = *(const bf8_t*)&Al[buf][(wr*64+m*16+rl)*40 + kseg];
    #pragma unroll
    for(int n=0;n<4;n++) bfr[n] = *(const bf8_t*)&Bl[buf][(wc*64+n*16+rl)*40 + kseg];
    #pragma unroll
    for(int m=0;m<4;m++)
      #pragma unroll
      for(int n=0;n<4;n++)
        acc[m][n] = __builtin_amdgcn_mfma_f32_16x16x32_bf16(af[m], bfr[n], acc[m][n], 0,0,0);
    __syncthreads();
    if(more){ store(buf^1); __syncthreads(); }
    buf^=1;
  }
  int orow = (lane>>4)*4;
  #pragma unroll
  for(int m=0;m<4;m++){
    #pragma unroll
    for(int n=0;n<4;n++){
      int l = l0 + wc*64 + n*16 + rl;
      #pragma unroll
      for(int r=0;r<4;r++){
        int o = o0 + wr*64 + m*16 + orow + r;
        float v = acc[m][n][r];
        if(o<512) xi0[((size_t)(b*512)+o    )*4096 + l] = v;
        else      z  [((size_t)(b*512)+o-512)*4096 + l] = v;
      }
    }
  }
}

// ---------------- causal depthwise conv1d (k=4) + silu, (B,512,L) c-major ----------------
__global__ __launch_bounds__(256) void conv1d_silu(const float* __restrict__ xi0,
    const float* __restrict__ cw, const float* __restrict__ cb, float* __restrict__ xi){
  int e = blockIdx.x*256 + threadIdx.x;   // 4*512*4096
  int l = e & 4095, d = (e>>12)&511;
  float acc = cb[d];
  #pragma unroll
  for(int k=0;k<4;k++){
    int ls = l-3+k;
    if(ls>=0) acc += cw[d*4+k]*xi0[e-3+k];
  }
  xi[e] = silu_f(acc);
}

// ---------------- GEMM: x_dbl = xi @ xproj^T (16384 x 48 x 512), out (B,L,48) ----------------
__global__ __launch_bounds__(256) void gemm_xdbl(const float* __restrict__ xi,
    const float* __restrict__ xpw, float* __restrict__ xdbl){
  int blk=blockIdx.x; int b=blk>>6, l0=(blk&63)<<6;
  __shared__ __align__(16) float a_t[64][64];
  __shared__ float wch[48][65];
  int t=threadIdx.x, lq=t>>4, oq=t&15;
  float acc[12];
  #pragma unroll
  for(int j=0;j<12;j++) acc[j]=0.f;
  for(int kc=0;kc<8;kc++){
    __syncthreads();
    for(int i=t;i<4096;i+=256){ int k=i>>6,l=i&63; a_t[k][l]=xi[((size_t)(b*512)+kc*64+k)*4096 + l0+l]; }
    for(int i=t;i<3072;i+=256){ int r=i>>6,k=i&63; wch[r][k]=xpw[r*512 + kc*64 + k]; }
    __syncthreads();
    for(int k=0;k<64;k++){
      const float4 uv = *(const float4*)&a_t[k][lq<<2];
      float uvf[4]; uvf[0]=uv.x; uvf[1]=uv.y; uvf[2]=uv.z; uvf[3]=uv.w;
      float wv[3];
      #pragma unroll
      for(int j=0;j<3;j++) wv[j]=wch[oq*3+j][k];
      #pragma unroll
      for(int ii=0;ii<4;ii++)
        #pragma unroll
        for(int jj=0;jj<3;jj++)
          acc[ii*3+jj]=fmaf(uvf[ii],wv[jj],acc[ii*3+jj]);
    }
  }
  #pragma unroll
  for(int ii=0;ii<4;ii++)
    #pragma unroll
    for(int jj=0;jj<3;jj++)
      xdbl[((size_t)(b*4096)+l0+(lq<<2)+ii)*48 + oq*3+jj]=acc[ii*3+jj];
}

// ---------------- dt = softplus(xdbl[:, :16] @ dt_w^T + dt_b), out (B,512,L) c-major ----------------
__global__ __launch_bounds__(256) void dtproj(const float* __restrict__ xdbl,
    const float* __restrict__ dtw, const float* __restrict__ dtb, float* __restrict__ dt){
  int blk=blockIdx.x; int b=blk>>6, l0=(blk&63)<<6;
  __shared__ float xl[64][17];
  __shared__ float wl[512][17];
  __shared__ float bl[512];
  for(int i=threadIdx.x;i<1024;i+=256){ int l=i>>4,r=i&15; xl[l][r]=xdbl[((size_t)(b*4096)+l0+l)*48 + r]; }
  for(int i=threadIdx.x;i<8192;i+=256){ int d=i>>4,r=i&15; wl[d][r]=dtw[i]; }
  for(int i=threadIdx.x;i<512;i+=256) bl[i]=dtb[i];
  __syncthreads();
  for(int j=threadIdx.x;j<32768;j+=256){
    int d=j>>6, l=j&63;
    float acc=bl[d];
    #pragma unroll
    for(int r=0;r<16;r++) acc=fmaf(xl[l][r], wl[d][r], acc);
    float sp = (acc>20.f)? acc : log1pf(__expf(acc));
    dt[((size_t)(b*512)+d)*4096 + l0 + l]=sp;
  }
}

// ================= chunk-parallel selective scan (8 chunks of 512) =================
__global__ __launch_bounds__(64) void m1_scan_p1(
    const float* __restrict__ dt, const float* __restrict__ xi,
    const float* __restrict__ xdbl, const float* __restrict__ Alog,
    float* __restrict__ Pbuf, float* __restrict__ qbuf){
  int blk=blockIdx.x;                  // (b<<10)|(g<<3)|c
  int c = blk&7, g=(blk>>3)&127, b=blk>>10;
  int lane=threadIdx.x, ds=lane>>4, s=lane&15;
  int d = g*4+ds;
  float A2 = -__expf(Alog[d*16+s]) * 1.44269504088896f;
  const size_t base_dl = ((size_t)b*512 + g*4)*4096;
  const float* xb = xdbl + (size_t)b*4096*48;
  __shared__ __align__(16) float dxl[2][4][136];
  __shared__ __align__(16) float Bl[2][64][20];
  int row = lane>>4, c4 = (lane&15)<<2;
  float4 rdt, rxi, rB[4];
  auto issue=[&](int l0){
    size_t o = base_dl + (size_t)row*4096 + l0 + c4;
    rdt = *(const float4*)(dt + o);
    rxi = *(const float4*)(xi + o);
    #pragma unroll
    for(int q=0;q<4;q++){
      int idx=q*64+lane, r=idx>>2, quad=idx&3;
      rB[q] = *(const float4*)(xb + (size_t)(l0+r)*48 + 16 + quad*4);
    }
  };
  auto store=[&](int buf){
    *(float4*)&dxl[buf][row][2*c4]   = make_float4(rdt.x, rxi.x, rdt.y, rxi.y);
    *(float4*)&dxl[buf][row][2*c4+4] = make_float4(rdt.z, rxi.z, rdt.w, rxi.w);
    #pragma unroll
    for(int q=0;q<4;q++){
      int idx=q*64+lane, r=idx>>2, quad=idx&3;
      *(float4*)&Bl[buf][r][quad*4]=rB[q];
    }
  };
  float P=1.f, qacc=0.f;
  int l0base = c*512;
  issue(l0base); store(0); __syncthreads();
  for(int ck=0;ck<8;ck++){
    int buf=ck&1; bool more=(ck+1)<8;
    if(more) issue(l0base+((ck+1)<<6));
    #pragma unroll 4
    for(int j4=0;j4<16;j4++){
      const float4 a  = *(const float4*)&dxl[buf][ds][8*j4];
      const float4 c2 = *(const float4*)&dxl[buf][ds][8*j4+4];
      {
        float dA=exp2f(a.x*A2);  P*=dA;  qacc=fmaf(dA,qacc,a.x*a.y*Bl[buf][4*j4+0][s]);
      }{
        float dA=exp2f(a.z*A2);  P*=dA;  qacc=fmaf(dA,qacc,a.z*a.w*Bl[buf][4*j4+1][s]);
      }{
        float dA=exp2f(c2.x*A2); P*=dA;  qacc=fmaf(dA,qacc,c2.x*c2.y*Bl[buf][4*j4+2][s]);
      }{
        float dA=exp2f(c2.z*A2); P*=dA;  qacc=fmaf(dA,qacc,c2.z*c2.w*Bl[buf][4*j4+3][s]);
      }
    }
    __syncthreads();
    if(more){ store(buf^1); __syncthreads(); }
  }
  size_t oidx = (((size_t)(b*128+g))*8+c)*64 + lane;
  Pbuf[oidx]=P; qbuf[oidx]=qacc;
}

__global__ __launch_bounds__(256) void m1_scan_mid(
    const float* __restrict__ Pbuf, const float* __restrict__ qbuf,
    float* __restrict__ hstart){
  int tid = blockIdx.x*256 + threadIdx.x;   // 32768
  int lane = tid&63, bg = tid>>6;
  size_t base = (size_t)bg*8*64 + lane;
  float h=0.f;
  #pragma unroll
  for(int c=0;c<8;c++){
    size_t idx = base + (size_t)c*64;
    hstart[idx]=h;
    h = fmaf(Pbuf[idx], h, qbuf[idx]);
  }
}

__global__ __launch_bounds__(64) void m1_scan_p2(
    const float* __restrict__ dt, const float* __restrict__ xi, const float* __restrict__ z,
    const float* __restrict__ xdbl, const float* __restrict__ Alog, const float* __restrict__ Dp,
    const float* __restrict__ hstart, float* __restrict__ y){
  int blk=blockIdx.x;                  // (b<<10)|(g<<3)|c
  int c = blk&7, g=(blk>>3)&127, b=blk>>10;
  int dbase = g*4;
  int lane = threadIdx.x;
  int ds = lane>>4, s = lane&15;
  int d = dbase + ds;
  float A2 = -__expf(Alog[d*16+s]) * 1.44269504088896f;
  float D4[4];
  #pragma unroll
  for(int dd=0;dd<4;dd++) D4[dd]=Dp[dbase+dd];
  const size_t base_dl = ((size_t)b*512 + dbase)*4096;
  const float* xb = xdbl + (size_t)b*4096*48;

  __shared__ __align__(16) float  dxl[2][4][136];
  __shared__ __align__(16) float  zl [2][4][68];
  __shared__ __align__(16) float4 bcl4[2][64][9];
  __shared__ __align__(16) float4 pl4[16][4];

  int row = lane>>4, c4 = (lane&15)<<2;
  float4 rdt, rxi, rz;
  float2 rb[8], rc[8];

  auto issue_loads=[&](int l0){
    size_t o = base_dl + (size_t)row*4096 + l0 + c4;
    rdt = *(const float4*)(dt + o);
    rxi = *(const float4*)(xi + o);
    rz  = *(const float4*)(z  + o);
    #pragma unroll
    for(int q=0;q<8;q++){
      int r = q*8 + (lane>>3), s2 = (lane&7)*2;
      const float* rowp = xb + (size_t)(l0+r)*48;
      rb[q] = *(const float2*)(rowp + 16 + s2);
      rc[q] = *(const float2*)(rowp + 32 + s2);
    }
  };
  auto store_lds=[&](int buf){
    *(float4*)&dxl[buf][row][2*c4]   = make_float4(rdt.x, rxi.x, rdt.y, rxi.y);
    *(float4*)&dxl[buf][row][2*c4+4] = make_float4(rdt.z, rxi.z, rdt.w, rxi.w);
    *(float4*)&zl[buf][row][c4]      = rz;
    #pragma unroll
    for(int q=0;q<8;q++){
      int r = q*8 + (lane>>3), s2h = lane&7;
      bcl4[buf][r][s2h] = make_float4(rb[q].x, rc[q].x, rb[q].y, rc[q].y);
    }
  };

  float h = hstart[(((size_t)(b*128+g))*8+c)*64 + lane];
  int lbase = c*512;
  issue_loads(lbase); store_lds(0); __syncthreads();
  for(int ck=0;ck<8;ck++){
    int buf = ck&1;
    bool more = (ck+1)<8;
    if(more) issue_loads(lbase+((ck+1)<<6));
    const char* bcbase = (const char*)&bcl4[buf][0][s>>1] + (s&1)*8;
    #pragma unroll 4
    for(int j4=0;j4<16;j4++){
      const float4 a  = *(const float4*)&dxl[buf][ds][8*j4];
      const float4 c2 = *(const float4*)&dxl[buf][ds][8*j4+4];
      float4 pacc;
      {
        float2 bc = *(const float2*)(bcbase + (size_t)(4*j4+0)*144);
        float dA = exp2f(a.x*A2);
        h = fmaf(dA, h, a.x*a.y*bc.x);
        pacc.x = row_sum16(h*bc.y);
      }
      {
        float2 bc = *(const float2*)(bcbase + (size_t)(4*j4+1)*144);
        float dA = exp2f(a.z*A2);
        h = fmaf(dA, h, a.z*a.w*bc.x);
        pacc.y = row_sum16(h*bc.y);
      }
      {
        float2 bc = *(const float2*)(bcbase + (size_t)(4*j4+2)*144);
        float dA = exp2f(c2.x*A2);
        h = fmaf(dA, h, c2.x*c2.y*bc.x);
        pacc.z = row_sum16(h*bc.y);
      }
      {
        float2 bc = *(const float2*)(bcbase + (size_t)(4*j4+3)*144);
        float dA = exp2f(c2.z*A2);
        h = fmaf(dA, h, c2.z*c2.w*bc.x);
        pacc.w = row_sum16(h*bc.y);
      }
      if(s==15) pl4[j4][ds] = pacc;
    }
    __syncthreads();
    int l0 = lbase + (ck<<6);
    int t = lane;
    #pragma unroll
    for(int dd=0;dd<4;dd++){
      float ps  = ((const float*)&pl4[t>>2][dd])[t&3];
      float xiv = dxl[buf][dd][2*t+1];
      float zv  = zl[buf][dd][t];
      y[base_dl + (size_t)dd*4096 + l0 + t] = (ps + xiv*D4[dd]) * silu_f(zv);
    }
    if(more) store_lds(buf^1);
    __syncthreads();
  }
}

// ---------------- fold out_w over the 4 direction groups: W'(64,512) ----------------
__global__ __launch_bounds__(256) void fold_w(const float* __restrict__ ow, float* __restrict__ wf){
  int i = blockIdx.x*256 + threadIdx.x;   // 32768
  if(i>=32768) return;
  int c = i>>9, d2 = i&511;
  wf[i] = ow[(c)*512+d2] + ow[(64+c)*512+d2] + ow[(128+c)*512+d2] + ow[(192+c)*512+d2];
}

// ---------------- GEMM: res = (y @ W'^T) * fo2s ; y (B,512,L), out res (B,64,L) ----------------
__global__ __launch_bounds__(256) void gemm_res(const float* __restrict__ y,
    const float* __restrict__ wf, const float* __restrict__ fo2s, float* __restrict__ res){
  int blk=blockIdx.x; int b=blk>>6, l0=(blk&63)<<6;
  __shared__ __align__(16) float a_t[64][64];
  __shared__ float wch[64][65];
  __shared__ float o_t[64][64];
  int t=threadIdx.x, lq=t>>4, cq=t&15;
  float acc[16];
  #pragma unroll
  for(int j=0;j<16;j++) acc[j]=0.f;
  for(int kc=0;kc<8;kc++){
    __syncthreads();
    for(int i=t;i<4096;i+=256){ int k=i>>6,l=i&63; a_t[k][l]=y[((size_t)(b*512)+kc*64+k)*4096 + l0+l]; }
    for(int i=t;i<4096;i+=256){ int r=i>>6,k=i&63; wch[r][k]=wf[r*512 + kc*64 + k]; }
    __syncthreads();
    for(int k=0;k<64;k++){
      const float4 uv = *(const float4*)&a_t[k][lq<<2];
      float uvf[4]; uvf[0]=uv.x; uvf[1]=uv.y; uvf[2]=uv.z; uvf[3]=uv.w;
      float wv[4];
      #pragma unroll
      for(int j=0;j<4;j++) wv[j]=wch[(cq<<2)+j][k];
      #pragma unroll
      for(int ii=0;ii<4;ii++)
        #pragma unroll
        for(int jj=0;jj<4;jj++)
          acc[ii*4+jj]=fmaf(uvf[ii],wv[jj],acc[ii*4+jj]);
    }
  }
  __syncthreads();
  #pragma unroll
  for(int ii=0;ii<4;ii++)
    #pragma unroll
    for(int jj=0;jj<4;jj++)
      o_t[(cq<<2)+jj][(lq<<2)+ii]=acc[ii*4+jj];
  __syncthreads();
  for(int i=t;i<4096;i+=256){
    int o=i>>6,l=i&63;
    size_t idx=((size_t)(b*64+o))*4096 + l0 + l;
    res[idx]=o_t[o][l]*fo2s[idx];
  }
}

// ---------------- per (b,c) spatial mean ----------------
__global__ __launch_bounds__(256) void colmean(const float* __restrict__ res, float* __restrict__ fm){
  int bc = blockIdx.x;
  const float* p = res + (size_t)bc*4096;
  float s=0;
  for(int i=threadIdx.x;i<4096;i+=256) s+=p[i];
  __shared__ float ls[256];
  ls[threadIdx.x]=s; __syncthreads();
  for(int st=128;st>0;st>>=1){ if(threadIdx.x<st) ls[threadIdx.x]+=ls[threadIdx.x+st]; __syncthreads(); }
  if(threadIdx.x==0) fm[bc]=ls[0]*(1.f/4096.f);
}

// ---------------- tiny mamba2 over channel sequence (L=64, d_model=2, d_inner=4) ----------------
__global__ __launch_bounds__(64) void mamba2_kernel(const float* __restrict__ fm,
    const float* __restrict__ in_w, const float* __restrict__ cw, const float* __restrict__ cb,
    const float* __restrict__ xp, const float* __restrict__ dtw, const float* __restrict__ dtb,
    const float* __restrict__ Alog, const float* __restrict__ Dp, const float* __restrict__ ow,
    float* __restrict__ fsum){
  int b = blockIdx.x; int t = threadIdx.x;   // 0..63
  __shared__ float xi0m[64][4], xim[64][4], dtm[64][4], xbl[64][33], ym[64][4];
  float a0 = fm[b*64+t], a1 = fm[b*64 + 63-t];
  float zreg[4];
  #pragma unroll
  for(int d2=0;d2<4;d2++){
    xi0m[t][d2] = in_w[d2*2+0]*a0 + in_w[d2*2+1]*a1;
    zreg[d2]    = in_w[(4+d2)*2+0]*a0 + in_w[(4+d2)*2+1]*a1;
  }
  __syncthreads();
  float xir[4];
  #pragma unroll
  for(int d2=0;d2<4;d2++){
    float acc=cb[d2];
    #pragma unroll
    for(int k=0;k<4;k++){
      int srow=t-3+k;
      if(srow>=0) acc += cw[d2*4+k]*xi0m[srow][d2];
    }
    xir[d2]=silu_f(acc);
    xim[t][d2]=xir[d2];
  }
  for(int j=0;j<33;j++){
    float acc=0;
    #pragma unroll
    for(int d2=0;d2<4;d2++) acc += xp[j*4+d2]*xir[d2];
    xbl[t][j]=acc;
  }
  #pragma unroll
  for(int d2=0;d2<4;d2++){
    float v = xbl[t][0]*dtw[d2] + dtb[d2];
    dtm[t][d2] = (v>20.f)? v : log1pf(__expf(v));
  }
  __syncthreads();
  int dd=t>>4, s=t&15;
  float A2 = -__expf(Alog[dd*16+s]) * 1.44269504088896f;
  float h=0.f;
  for(int c=0;c<64;c++){
    float dtv=dtm[c][dd];
    float dA=exp2f(dtv*A2);
    h = fmaf(dA, h, dtv*xim[c][dd]*xbl[c][1+s]);
    float p = h*xbl[c][17+s];
    p += __shfl_xor(p,1,16);
    p += __shfl_xor(p,2,16);
    p += __shfl_xor(p,4,16);
    p += __shfl_xor(p,8,16);
    if(s==0) ym[c][dd]=p;
  }
  __syncthreads();
  float os=0.f;
  #pragma unroll
  for(int d2=0;d2<4;d2++){
    float yv = (ym[t][d2] + xim[t][d2]*Dp[d2]) * silu_f(zreg[d2]);
    os += yv * (ow[d2] + ow[4+d2]);
  }
  fsum[b*64+t]=os;
}

// ---------------- foss = res*(1+foc) ; x2 = outproj(foss) + x ----------------
__global__ __launch_bounds__(256) void outproj_kernel(const float* __restrict__ res,
    const float* __restrict__ fsum, const float* __restrict__ opw, const float* __restrict__ opb,
    const float* __restrict__ x, float* __restrict__ x2){
  int bh=blockIdx.x; int b=bh>>6,h=bh&63;
  __shared__ float tile[64][64];
  __shared__ float wl[4096];
  for(int i=threadIdx.x;i<4096;i+=256) wl[i]=opw[i];
  for(int i=threadIdx.x;i<4096;i+=256){
    int c=i>>6,w=i&63;
    tile[c][w]=res[((size_t)(b*64+c))*4096 + h*64 + w]*(1.f+fsum[b*64+c]);
  }
  __syncthreads();
  int px=threadIdx.x&63, og=threadIdx.x>>6;
  float acc[16];
  #pragma unroll
  for(int j=0;j<16;j++) acc[j]=0.f;
  for(int c=0;c<64;c++){
    float v=tile[c][px];
    #pragma unroll
    for(int j=0;j<16;j++) acc[j]=fmaf(wl[(og*16+j)*64+c],v,acc[j]);
  }
  for(int j=0;j<16;j++){
    int o=og*16+j;
    size_t idx=((size_t)(b*64+o))*4096 + h*64 + px;
    x2[idx]=acc[j]+opb[o]+x[idx];
  }
}

// ---------------- LN2 apply + ffn_in (64->256) ----------------
__global__ __launch_bounds__(256) void ffn_in_kernel(const float* __restrict__ x2,
    const float* __restrict__ n2w, const float* __restrict__ n2b,
    const float* __restrict__ fiw, const float* __restrict__ fib,
    const float* __restrict__ mu2, const float* __restrict__ rstd2,
    float* __restrict__ g){
  int bh=blockIdx.x; int b=bh>>6,h=bh&63;
  __shared__ float tile[64][64];
  __shared__ float wl[256*64];
  float m=mu2[b], rs=rstd2[b];
  for(int i=threadIdx.x;i<4096;i+=256){
    int c=i>>6,w=i&63;
    size_t sp=(size_t)c*4096 + h*64 + w;
    tile[c][w]=(x2[(size_t)b*262144+sp]-m)*rs*n2w[sp]+n2b[sp];
  }
  for(int i=threadIdx.x;i<16384;i+=256) wl[i]=fiw[i];
  __syncthreads();
  int px=threadIdx.x&63, og=threadIdx.x>>6;
  for(int half=0;half<2;half++){
    float acc[32];
    #pragma unroll
    for(int j=0;j<32;j++) acc[j]=0.f;
    int ob = half*128 + og*32;
    for(int c=0;c<64;c++){
      float v=tile[c][px];
      #pragma unroll
      for(int j=0;j<32;j++) acc[j]=fmaf(wl[(ob+j)*64+c],v,acc[j]);
    }
    for(int j=0;j<32;j++){
      int o=ob+j;
      g[((size_t)(b*256+o))*4096 + h*64 + px]=acc[j]+fib[o];
    }
  }
}

// ---------------- ffn depthwise 3x3 + gelu-gate ----------------
__global__ __launch_bounds__(256) void ffn_dw_gate(const float* __restrict__ g,
    const float* __restrict__ dww, const float* __restrict__ dwb, float* __restrict__ gm){
  int e = blockIdx.x*256 + threadIdx.x;   // 4*128*4096
  int sp = e & 4095, j = (e>>12)&127, b = e>>19;
  int h = sp>>6, w = sp&63;
  float v[2];
  #pragma unroll
  for(int half=0;half<2;half++){
    int ch = j + half*128;
    const float* gp = g + ((size_t)(b*256+ch))*4096;
    float acc = dwb[ch];
    #pragma unroll
    for(int kh=0;kh<3;kh++){
      int ih=h+kh-1; if(ih<0||ih>63) continue;
      #pragma unroll
      for(int kw=0;kw<3;kw++){
        int iw=w+kw-1; if(iw<0||iw>63) continue;
        acc += dww[ch*9+kh*3+kw]*gp[ih*64+iw];
      }
    }
    v[half]=acc;
  }
  float ge = 0.5f*v[0]*(1.f+erff(v[0]*0.70710678f));
  gm[((size_t)(b*128+j))*4096 + sp] = ge*v[1];
}

// ---------------- ffn_out (128->64) + bias + residual add -> d_out ----------------
__global__ __launch_bounds__(256) void ffn_out_kernel(const float* __restrict__ gm,
    const float* __restrict__ fow, const float* __restrict__ fob,
    const float* __restrict__ x2, float* __restrict__ out){
  int bh=blockIdx.x; int b=bh>>6,h=bh&63;
  __shared__ float tile[128][64];
  __shared__ float wl[64*128];
  for(int i=threadIdx.x;i<8192;i+=256){
    int c=i>>6,w=i&63;
    tile[c][w]=gm[((size_t)(b*128+c))*4096 + h*64 + w];
  }
  for(int i=threadIdx.x;i<8192;i+=256) wl[i]=fow[i];
  __syncthreads();
  int px=threadIdx.x&63, og=threadIdx.x>>6;
  float acc[16];
  #pragma unroll
  for(int j=0;j<16;j++) acc[j]=0.f;
  for(int c=0;c<128;c++){
    float v=tile[c][px];
    #pragma unroll
    for(int j=0;j<16;j++) acc[j]=fmaf(wl[(og*16+j)*128+c],v,acc[j]);
  }
  for(int j=0;j<16;j++){
    int o=og*16+j;
    size_t idx=((size_t)(b*64+o))*4096 + h*64 + px;
    out[idx]=acc[j]+fob[o]+x2[idx];
  }
}

extern "C" void kernel_launch(void* const* d_in, const int* in_sizes, int n_in,
                              void* d_out, int out_size, void* d_ws, size_t ws_size,
                              hipStream_t stream){
  const float* x      = (const float*)d_in[0];
  const float* n1w    = (const float*)d_in[1];
  const float* n1b    = (const float*)d_in[2];
  const float* n2w    = (const float*)d_in[3];
  const float* n2b    = (const float*)d_in[4];
  const float* ipw    = (const float*)d_in[5];
  const float* ipb    = (const float*)d_in[6];
  const float* dww    = (const float*)d_in[7];
  const float* dwb    = (const float*)d_in[8];
  const float* opw    = (const float*)d_in[9];
  const float* opb    = (const float*)d_in[10];
  const float* m1_inw = (const float*)d_in[11];
  const float* m1_cw  = (const float*)d_in[12];
  const float* m1_cb  = (const float*)d_in[13];
  const float* m1_xp  = (const float*)d_in[14];
  const float* m1_dtw = (const float*)d_in[15];
  const float* m1_dtb = (const float*)d_in[16];
  const float* m1_Al  = (const float*)d_in[17];
  const float* m1_D   = (const float*)d_in[18];
  const float* m1_ow  = (const float*)d_in[19];
  const float* m2_inw = (const float*)d_in[20];
  const float* m2_cw  = (const float*)d_in[21];
  const float* m2_cb  = (const float*)d_in[22];
  const float* m2_xp  = (const float*)d_in[23];
  const float* m2_dtw = (const float*)d_in[24];
  const float* m2_dtb = (const float*)d_in[25];
  const float* m2_Al  = (const float*)d_in[26];
  const float* m2_D   = (const float*)d_in[27];
  const float* m2_ow  = (const float*)d_in[28];
  const float* fiw    = (const float*)d_in[29];
  const float* fib    = (const float*)d_in[30];
  const float* fdw    = (const float*)d_in[31];
  const float* fdb    = (const float*)d_in[32];
  const float* fow    = (const float*)d_in[33];
  const float* fob    = (const float*)d_in[34];
  float* out = (float*)d_out;
  float* ws  = (float*)d_ws;

  // workspace layout (floats), aliased.
  float* mu1   = ws + 0;  float* rstd1 = ws + 4;
  float* mu2   = ws + 8;  float* rstd2 = ws + 12;
  float* fmean = ws + 64;    // 256
  float* fsum  = ws + 320;   // 256
  float* wfold = ws + 1024;  // 32768
  float* lnpart= ws + 33792; // 512 floats (256 float2)
  float* fo1raw= ws + 36864;           // 1M   (later: res)
  float* fo2s  = fo1raw + 1048576;     // 1M
  float* fo1s  = fo2s   + 1048576;     // 1M  (later: Pbuf/qbuf/hstart for scan)
  float* fo1t  = fo1s   + 1048576;     // 1M
  float* ubuf  = fo1t   + 1048576;     // (u_bf16; later dt 8M; later g 4M)
  float* dtbuf = ubuf;                 // (B,512,L)
  float* gbuf  = ubuf;                 // (B,256,L)
  float* xi0   = ubuf + 8388608;       // 8M  (later: y)
  float* ybuf  = xi0;
  float* zbuf  = xi0  + 8388608;       // 8M  (later: gm 2M)
  float* gmbuf = zbuf;
  float* xibuf = zbuf + 8388608;       // 8M
  float* xdbl  = xibuf+ 8388608;       // 786432
  float* x2    = xdbl + 786432;        // 1M
  float* res   = fo1raw;
  float* Pbuf   = fo1s;
  float* qbuf   = fo1s + 262144;
  float* hstart = fo1s + 524288;
  uint*   u_bf  = (uint*)ubuf;               // (B,4096,256) bf16 = 8MB
  ushort* w_bf  = (ushort*)(x2 + 1048576);   // 1024x256 bf16 = 512KB (tail)

  hipLaunchKernelGGL(ln_part, dim3(256), dim3(256), 0, stream, x, (float2*)lnpart);
  hipLaunchKernelGGL(ln_fin, dim3(4), dim3(64), 0, stream, (const float2*)lnpart, mu1, rstd1);
  hipLaunchKernelGGL(cvt_w_bf, dim3(512), dim3(256), 0, stream, m1_inw, (uint*)w_bf);
  hipLaunchKernelGGL(ln1_inproj, dim3(256), dim3(256), 0, stream,
                     x, n1w, n1b, ipw, ipb, mu1, rstd1, fo1raw, fo2s);
  hipLaunchKernelGGL(dwconv_silu_tr, dim3(256), dim3(256), 0, stream,
                     fo1raw, dww, dwb, fo1s, fo1t);
  hipLaunchKernelGGL(gather_u_t, dim3(1024), dim3(256), 0, stream, fo1s, fo1t, u_bf);
  hipLaunchKernelGGL(gemm_xz_mfma, dim3(128, 8), dim3(256), 0, stream,
                     (const ushort*)u_bf, w_bf, xi0, zbuf);
  hipLaunchKernelGGL(conv1d_silu, dim3(32768), dim3(256), 0, stream, xi0, m1_cw, m1_cb, xibuf);
  hipLaunchKernelGGL(gemm_xdbl, dim3(256), dim3(256), 0, stream, xibuf, m1_xp, xdbl);
  hipLaunchKernelGGL(dtproj, dim3(256), dim3(256), 0, stream, xdbl, m1_dtw, m1_dtb, dtbuf);
  hipLaunchKernelGGL(fold_w, dim3(128), dim3(256), 0, stream, m1_ow, wfold);
  hipLaunchKernelGGL(m1_scan_p1, dim3(4096), dim3(64), 0, stream,
                     dtbuf, xibuf, xdbl, m1_Al, Pbuf, qbuf);
  hipLaunchKernelGGL(m1_scan_mid, dim3(128), dim3(256), 0, stream, Pbuf, qbuf, hstart);
  hipLaunchKernelGGL(m1_scan_p2, dim3(4096), dim3(64), 0, stream,
                     dtbuf, xibuf, zbuf, xdbl, m1_Al, m1_D, hstart, ybuf);
  hipLaunchKernelGGL(gemm_res, dim3(256), dim3(256), 0, stream, ybuf, wfold, fo2s, res);
  hipLaunchKernelGGL(colmean, dim3(256), dim3(256), 0, stream, res, fmean);
  hipLaunchKernelGGL(mamba2_kernel, dim3(4), dim3(64), 0, stream,
                     fmean, m2_inw, m2_cw, m2_cb, m2_xp, m2_dtw, m2_dtb, m2_Al, m2_D, m2_ow, fsum);
  hipLaunchKernelGGL(outproj_kernel, dim3(256), dim3(256), 0, stream,
                     res, fsum, opw, opb, x, x2);
  hipLaunchKernelGGL(ln_part, dim3(256), dim3(256), 0, stream, x2, (float2*)lnpart);
  hipLaunchKernelGGL(ln_fin, dim3(4), dim3(64), 0, stream, (const float2*)lnpart, mu2, rstd2);
  hipLaunchKernelGGL(ffn_in_kernel, dim3(256), dim3(256), 0, stream,
                     x2, n2w, n2b, fiw, fib, mu2, rstd2, gbuf);
  hipLaunchKernelGGL(ffn_dw_gate, dim3(8192), dim3(256), 0, stream, gbuf, fdw, fdb, gmbuf);
  hipLaunchKernelGGL(ffn_out_kernel, dim3(256), dim3(256), 0, stream, gmbuf, fow, fob, x2, out);
}

// Round 5
// 491.341 us; speedup vs baseline: 4.2086x; 1.1306x over previous
//
#include <hip/hip_runtime.h>
#include <math.h>

// OSS / VMamba-style block. B=4, C=64, H=W=64, L=4096, d_inner=512, D_STATE=16.
// R1: scan DPP reduce. R2: two-stage LN; chunk-parallel scan. R3: gemm_xz MFMA.
// R4: scan v3 — 16ch x 4states/lane, 32 chunks of 128, barrier-free 1-wave blocks,
//     quad_perm reduce, z reg-prefetch. Replaces the 4ch/wave scan.

#define DEV static __device__ __forceinline__

DEV float silu_f(float x){ return x / (1.f + __expf(-x)); }

DEV ushort f2bf(float f){
  uint u = __float_as_uint(f);
  uint r = (u + 0x7FFF + ((u>>16)&1)) >> 16;
  return (ushort)r;
}
DEV uint f2bf2(float lo, float hi){
  return (uint)f2bf(lo) | ((uint)f2bf(hi)<<16);
}

typedef __attribute__((ext_vector_type(8))) short bf8_t;
typedef __attribute__((ext_vector_type(4))) float f4_t;

// quad (4-lane) sum via DPP quad_perm; every lane of the quad gets the sum
DEV float quad_sum4(float v){
  v += __int_as_float(__builtin_amdgcn_update_dpp(0, __float_as_int(v), 0xB1, 0xF, 0xF, false)); // [1,0,3,2]
  v += __int_as_float(__builtin_amdgcn_update_dpp(0, __float_as_int(v), 0x4E, 0xF, 0xF, false)); // [2,3,0,1]
  return v;
}

// ---------------- LayerNorm stats, two-stage ----------------
__global__ __launch_bounds__(256) void ln_part(const float* __restrict__ x,
                                               float2* __restrict__ part){
  int blk = blockIdx.x; int b = blk>>6, pc = blk&63;
  const float* p = x + (size_t)b*262144 + (size_t)pc*4096;
  float s=0.f, s2=0.f;
  #pragma unroll
  for(int it=0; it<4; ++it){
    int i = threadIdx.x + it*256;
    float4 v = *(const float4*)(p + i*4);
    s  += v.x+v.y+v.z+v.w;
    s2 += v.x*v.x+v.y*v.y+v.z*v.z+v.w*v.w;
  }
  __shared__ float ls[256], ls2[256];
  ls[threadIdx.x]=s; ls2[threadIdx.x]=s2; __syncthreads();
  for(int st=128;st>0;st>>=1){
    if(threadIdx.x<st){ ls[threadIdx.x]+=ls[threadIdx.x+st]; ls2[threadIdx.x]+=ls2[threadIdx.x+st]; }
    __syncthreads();
  }
  if(threadIdx.x==0) part[blk]=make_float2(ls[0],ls2[0]);
}
__global__ __launch_bounds__(64) void ln_fin(const float2* __restrict__ part,
                                             float* __restrict__ mu, float* __restrict__ rstd){
  int b = blockIdx.x;
  float2 v = part[b*64+threadIdx.x];
  __shared__ double ds_[64], ds2_[64];
  ds_[threadIdx.x]=v.x; ds2_[threadIdx.x]=v.y; __syncthreads();
  for(int st=32;st>0;st>>=1){
    if(threadIdx.x<st){ ds_[threadIdx.x]+=ds_[threadIdx.x+st]; ds2_[threadIdx.x]+=ds2_[threadIdx.x+st]; }
    __syncthreads();
  }
  if(threadIdx.x==0){
    double m = ds_[0]*(1.0/262144.0);
    double var = ds2_[0]*(1.0/262144.0) - m*m;
    mu[b]=(float)m; rstd[b]=(float)(1.0/sqrt(var+1e-5));
  }
}

// ---------------- LN1 apply + inproj (64->128) + split, silu on fo2 ----------------
__global__ __launch_bounds__(256) void ln1_inproj(const float* __restrict__ x,
    const float* __restrict__ n1w, const float* __restrict__ n1b,
    const float* __restrict__ ipw, const float* __restrict__ ipb,
    const float* __restrict__ mu, const float* __restrict__ rstd,
    float* __restrict__ fo1_raw, float* __restrict__ fo2s){
  int bh = blockIdx.x; int b = bh>>6, h = bh&63;
  __shared__ float xn[64][64];
  __shared__ float wl[128*64];
  float m = mu[b], rs = rstd[b];
  for(int i=threadIdx.x;i<4096;i+=256){
    int c=i>>6, w=i&63;
    size_t sp=(size_t)c*4096 + h*64 + w;
    float v = x[(size_t)b*262144 + sp];
    xn[c][w] = (v-m)*rs*n1w[sp] + n1b[sp];
  }
  for(int i=threadIdx.x;i<8192;i+=256) wl[i]=ipw[i];
  __syncthreads();
  int px = threadIdx.x & 63, ob = (threadIdx.x>>6)*32;
  float acc[32];
  #pragma unroll
  for(int j=0;j<32;j++) acc[j]=0.f;
  for(int c=0;c<64;c++){
    float xv = xn[c][px];
    #pragma unroll
    for(int j=0;j<32;j++) acc[j] = fmaf(wl[(ob+j)*64+c], xv, acc[j]);
  }
  for(int j=0;j<32;j++){
    int o = ob+j;
    float v = acc[j] + ipb[o];
    if(o<64) fo1_raw[((size_t)(b*64+o))*4096 + h*64 + px] = v;
    else     fo2s  [((size_t)(b*64+o-64))*4096 + h*64 + px] = silu_f(v);
  }
}

// ---------------- depthwise 3x3 + silu, writes normal + transposed spatial ----------------
__global__ __launch_bounds__(256) void dwconv_silu_tr(const float* __restrict__ src_,
    const float* __restrict__ dww, const float* __restrict__ dwb,
    float* __restrict__ fo1s, float* __restrict__ fo1t){
  int bc = blockIdx.x; int c = bc & 63;
  const float* src = src_ + (size_t)bc*4096;
  float wk[9];
  #pragma unroll
  for(int k=0;k<9;k++) wk[k]=dww[c*9+k];
  float bias = dwb[c];
  __shared__ float tl[64][65];
  for(int i=threadIdx.x;i<4096;i+=256){
    int h=i>>6, w=i&63;
    float acc=bias;
    #pragma unroll
    for(int kh=0;kh<3;kh++){
      int ih=h+kh-1; if(ih<0||ih>63) continue;
      #pragma unroll
      for(int kw=0;kw<3;kw++){
        int iw=w+kw-1; if(iw<0||iw>63) continue;
        acc += wk[kh*3+kw]*src[ih*64+iw];
      }
    }
    tl[h][w] = silu_f(acc);
  }
  __syncthreads();
  float* ps = fo1s + (size_t)bc*4096;
  float* pt = fo1t + (size_t)bc*4096;
  for(int i=threadIdx.x;i<4096;i+=256){
    ps[i] = tl[i>>6][i&63];
    pt[i] = tl[i&63][i>>6];
  }
}

// ---------------- convert in_w to bf16 ----------------
__global__ __launch_bounds__(256) void cvt_w_bf(const float* __restrict__ w, uint* __restrict__ wb){
  int i = blockIdx.x*256 + threadIdx.x;   // 131072 pairs
  float2 v = *(const float2*)(w + 2*i);
  wb[i] = f2bf2(v.x, v.y);
}

// ---------------- gather u transposed: (B, L=4096, 256) bf16 ----------------
__global__ __launch_bounds__(256) void gather_u_t(const float* __restrict__ fo1s,
    const float* __restrict__ fo1t, uint* __restrict__ u_bf){
  int blk = blockIdx.x;             // ((b*4+part)<<6)|lt
  int lt = blk&63, part = (blk>>6)&3, b = blk>>8;
  int l0 = lt<<6;
  const float* s = (part<2)? fo1s : fo1t;
  bool rev = part&1;
  __shared__ float tl[64][65];
  for(int i=threadIdx.x;i<4096;i+=256){
    int c=i>>6, j=i&63;
    int l = l0 + j;
    int idx = rev ? (4095-l) : l;
    tl[c][j] = s[((size_t)(b*64+c))*4096 + idx];
  }
  __syncthreads();
  for(int i=threadIdx.x;i<2048;i+=256){
    int j = i>>5, cp = i&31;
    int l = l0 + j;
    u_bf[((size_t)(b*4096)+l)*128 + part*32 + cp] = f2bf2(tl[2*cp][j], tl[2*cp+1][j]);
  }
}

// ---------------- MFMA GEMM: xz = W(1024,256) x U^T ; U_t (B,4096,256) bf16 ----------------
__global__ __launch_bounds__(256) void gemm_xz_mfma(const ushort* __restrict__ u_bf,
    const ushort* __restrict__ w_bf, float* __restrict__ xi0, float* __restrict__ z){
  int blk = blockIdx.x; int b = blk>>5; int l0 = (blk&31)<<7;
  int o0 = blockIdx.y<<7;
  __shared__ ushort Al[2][5120];   // 128 rows x 32 k, stride 40
  __shared__ ushort Bl[2][5120];
  int t = threadIdx.x, lane = t&63, wid = t>>6;
  int wr = wid>>1, wc = wid&1;
  int rl = lane&15, kseg = (lane>>4)*8;
  f4_t acc[4][4];
  #pragma unroll
  for(int m=0;m<4;m++)
    #pragma unroll
    for(int n=0;n<4;n++) acc[m][n]=(f4_t){0.f,0.f,0.f,0.f};

  int r0 = t>>2, r1 = 64+(t>>2), seg = t&3;
  uint4 rA0,rA1,rB0,rB1;
  auto issue=[&](int kc){
    rA0 = *(const uint4*)&w_bf[(size_t)(o0+r0)*256 + kc*32 + seg*8];
    rA1 = *(const uint4*)&w_bf[(size_t)(o0+r1)*256 + kc*32 + seg*8];
    rB0 = *(const uint4*)&u_bf[((size_t)(b*4096)+l0+r0)*256 + kc*32 + seg*8];
    rB1 = *(const uint4*)&u_bf[((size_t)(b*4096)+l0+r1)*256 + kc*32 + seg*8];
  };
  auto store=[&](int buf){
    *(uint4*)&Al[buf][r0*40 + seg*8] = rA0;
    *(uint4*)&Al[buf][r1*40 + seg*8] = rA1;
    *(uint4*)&Bl[buf][r0*40 + seg*8] = rB0;
    *(uint4*)&Bl[buf][r1*40 + seg*8] = rB1;
  };
  issue(0); store(0); __syncthreads();
  int buf=0;
  for(int kc=0;kc<8;kc++){
    bool more = kc<7;
    if(more) issue(kc+1);
    bf8_t af[4], bfr[4];
    #pragma unroll
    for(int m=0;m<4;m++) af[m] = *(const bf8_t*)&Al[buf][(wr*64+m*16+rl)*40 + kseg];
    #pragma unroll
    for(int n=0;n<4;n++) bfr[n] = *(const bf8_t*)&Bl[buf][(wc*64+n*16+rl)*40 + kseg];
    #pragma unroll
    for(int m=0;m<4;m++)
      #pragma unroll
      for(int n=0;n<4;n++)
        acc[m][n] = __builtin_amdgcn_mfma_f32_16x16x32_bf16(af[m], bfr[n], acc[m][n], 0,0,0);
    __syncthreads();
    if(more){ store(buf^1); __syncthreads(); }
    buf^=1;
  }
  int orow = (lane>>4)*4;
  #pragma unroll
  for(int m=0;m<4;m++){
    #pragma unroll
    for(int n=0;n<4;n++){
      int l = l0 + wc*64 + n*16 + rl;
      #pragma unroll
      for(int r=0;r<4;r++){
        int o = o0 + wr*64 + m*16 + orow + r;
        float v = acc[m][n][r];
        if(o<512) xi0[((size_t)(b*512)+o    )*4096 + l] = v;
        else      z  [((size_t)(b*512)+o-512)*4096 + l] = v;
      }
    }
  }
}

// ---------------- causal depthwise conv1d (k=4) + silu, (B,512,L) c-major ----------------
__global__ __launch_bounds__(256) void conv1d_silu(const float* __restrict__ xi0,
    const float* __restrict__ cw, const float* __restrict__ cb, float* __restrict__ xi){
  int e = blockIdx.x*256 + threadIdx.x;   // 4*512*4096
  int l = e & 4095, d = (e>>12)&511;
  float acc = cb[d];
  #pragma unroll
  for(int k=0;k<4;k++){
    int ls = l-3+k;
    if(ls>=0) acc += cw[d*4+k]*xi0[e-3+k];
  }
  xi[e] = silu_f(acc);
}

// ---------------- GEMM: x_dbl = xi @ xproj^T (16384 x 48 x 512), out (B,L,48) ----------------
__global__ __launch_bounds__(256) void gemm_xdbl(const float* __restrict__ xi,
    const float* __restrict__ xpw, float* __restrict__ xdbl){
  int blk=blockIdx.x; int b=blk>>6, l0=(blk&63)<<6;
  __shared__ __align__(16) float a_t[64][64];
  __shared__ float wch[48][65];
  int t=threadIdx.x, lq=t>>4, oq=t&15;
  float acc[12];
  #pragma unroll
  for(int j=0;j<12;j++) acc[j]=0.f;
  for(int kc=0;kc<8;kc++){
    __syncthreads();
    for(int i=t;i<4096;i+=256){ int k=i>>6,l=i&63; a_t[k][l]=xi[((size_t)(b*512)+kc*64+k)*4096 + l0+l]; }
    for(int i=t;i<3072;i+=256){ int r=i>>6,k=i&63; wch[r][k]=xpw[r*512 + kc*64 + k]; }
    __syncthreads();
    for(int k=0;k<64;k++){
      const float4 uv = *(const float4*)&a_t[k][lq<<2];
      float uvf[4]; uvf[0]=uv.x; uvf[1]=uv.y; uvf[2]=uv.z; uvf[3]=uv.w;
      float wv[3];
      #pragma unroll
      for(int j=0;j<3;j++) wv[j]=wch[oq*3+j][k];
      #pragma unroll
      for(int ii=0;ii<4;ii++)
        #pragma unroll
        for(int jj=0;jj<3;jj++)
          acc[ii*3+jj]=fmaf(uvf[ii],wv[jj],acc[ii*3+jj]);
    }
  }
  #pragma unroll
  for(int ii=0;ii<4;ii++)
    #pragma unroll
    for(int jj=0;jj<3;jj++)
      xdbl[((size_t)(b*4096)+l0+(lq<<2)+ii)*48 + oq*3+jj]=acc[ii*3+jj];
}

// ---------------- dt = softplus(xdbl[:, :16] @ dt_w^T + dt_b), out (B,512,L) c-major ----------------
__global__ __launch_bounds__(256) void dtproj(const float* __restrict__ xdbl,
    const float* __restrict__ dtw, const float* __restrict__ dtb, float* __restrict__ dt){
  int blk=blockIdx.x; int b=blk>>6, l0=(blk&63)<<6;
  __shared__ float xl[64][17];
  __shared__ float wl[512][17];
  __shared__ float bl[512];
  for(int i=threadIdx.x;i<1024;i+=256){ int l=i>>4,r=i&15; xl[l][r]=xdbl[((size_t)(b*4096)+l0+l)*48 + r]; }
  for(int i=threadIdx.x;i<8192;i+=256){ int d=i>>4,r=i&15; wl[d][r]=dtw[i]; }
  for(int i=threadIdx.x;i<512;i+=256) bl[i]=dtb[i];
  __syncthreads();
  for(int j=threadIdx.x;j<32768;j+=256){
    int d=j>>6, l=j&63;
    float acc=bl[d];
    #pragma unroll
    for(int r=0;r<16;r++) acc=fmaf(xl[l][r], wl[d][r], acc);
    float sp = (acc>20.f)? acc : log1pf(__expf(acc));
    dt[((size_t)(b*512)+d)*4096 + l0 + l]=sp;
  }
}

// ================= scan v3: 32 chunks of 128; wave = 16 ch x 4 states =================
// blk = b*1024 + g*32 + c  (g: 16-channel group, c: chunk)
__global__ __launch_bounds__(64) void scan3_p1(
    const float* __restrict__ dt, const float* __restrict__ xi,
    const float* __restrict__ xdbl, const float* __restrict__ Alog,
    float4* __restrict__ Pbuf, float4* __restrict__ qbuf){
  int blk=blockIdx.x;
  int c=blk&31, g=(blk>>5)&31, b=blk>>10;
  int lane=threadIdx.x, ch=lane>>2, sq=lane&3;
  int d=g*16+ch;
  float4 Ar = *(const float4*)(Alog + d*16 + sq*4);
  float A2[4];
  A2[0]=-__expf(Ar.x)*1.44269504088896f;
  A2[1]=-__expf(Ar.y)*1.44269504088896f;
  A2[2]=-__expf(Ar.z)*1.44269504088896f;
  A2[3]=-__expf(Ar.w)*1.44269504088896f;
  __shared__ __align__(16) float dtxi[2][16][68];
  __shared__ __align__(16) float bl[2][32][17];
  const int l0c = c*128;
  const size_t dtrow = ((size_t)(b*512)+d)*4096;
  const float* xb = xdbl + (size_t)b*4096*48;
  float4 rdt[2], rxi[2], rb[2];
  auto issue=[&](int t){
    int l0 = l0c + t*32;
    #pragma unroll
    for(int it=0; it<2; ++it){
      size_t o = dtrow + l0 + it*16 + sq*4;
      rdt[it]=*(const float4*)(dt+o);
      rxi[it]=*(const float4*)(xi+o);
    }
    #pragma unroll
    for(int k=0;k<2;k++){
      int j=ch+k*16;
      rb[k]=*(const float4*)(xb + (size_t)(l0+j)*48 + 16 + sq*4);
    }
  };
  auto store=[&](int buf){
    #pragma unroll
    for(int it=0;it<2;++it){
      int base = it*32 + sq*8;
      *(float4*)&dtxi[buf][ch][base]   = make_float4(rdt[it].x, rxi[it].x, rdt[it].y, rxi[it].y);
      *(float4*)&dtxi[buf][ch][base+4] = make_float4(rdt[it].z, rxi[it].z, rdt[it].w, rxi[it].w);
    }
    #pragma unroll
    for(int k=0;k<2;k++)
      *(float4*)&bl[buf][ch+k*16][sq*4] = rb[k];
  };
  float P[4]={1.f,1.f,1.f,1.f}, q[4]={0.f,0.f,0.f,0.f};
  issue(0); store(0);
  for(int t=0;t<4;t++){
    int buf=t&1;
    if(t<3) issue(t+1);
    #pragma unroll 4
    for(int jp=0;jp<16;jp++){
      float4 dx = *(const float4*)&dtxi[buf][ch][jp*4];
      {
        float dtv=dx.x, u=dx.x*dx.y;
        float4 B4 = *(const float4*)&bl[buf][2*jp][sq*4];
        float Bv[4]={B4.x,B4.y,B4.z,B4.w};
        #pragma unroll
        for(int i=0;i<4;i++){ float dA=exp2f(dtv*A2[i]); P[i]*=dA; q[i]=fmaf(dA,q[i],u*Bv[i]); }
      }
      {
        float dtv=dx.z, u=dx.z*dx.w;
        float4 B4 = *(const float4*)&bl[buf][2*jp+1][sq*4];
        float Bv[4]={B4.x,B4.y,B4.z,B4.w};
        #pragma unroll
        for(int i=0;i<4;i++){ float dA=exp2f(dtv*A2[i]); P[i]*=dA; q[i]=fmaf(dA,q[i],u*Bv[i]); }
      }
    }
    if(t<3) store(buf^1);
  }
  int idx = blk*64 + lane;
  Pbuf[idx]=make_float4(P[0],P[1],P[2],P[3]);
  qbuf[idx]=make_float4(q[0],q[1],q[2],q[3]);
}

__global__ __launch_bounds__(256) void scan3_mid(const float4* __restrict__ Pbuf,
    const float4* __restrict__ qbuf, float4* __restrict__ hstart){
  int tid = blockIdx.x*256+threadIdx.x;  // 8192
  int lane = tid&63, sg = tid>>6;        // sg = b*32+g
  float4 h = make_float4(0.f,0.f,0.f,0.f);
  #pragma unroll
  for(int c=0;c<32;c++){
    int idx = (sg*32+c)*64 + lane;
    hstart[idx]=h;
    float4 P=Pbuf[idx], q=qbuf[idx];
    h.x = fmaf(P.x,h.x,q.x);
    h.y = fmaf(P.y,h.y,q.y);
    h.z = fmaf(P.z,h.z,q.z);
    h.w = fmaf(P.w,h.w,q.w);
  }
}

__global__ __launch_bounds__(64) void scan3_p2(
    const float* __restrict__ dt, const float* __restrict__ xi, const float* __restrict__ z,
    const float* __restrict__ xdbl, const float* __restrict__ Alog, const float* __restrict__ Dp,
    const float4* __restrict__ hstart, float* __restrict__ y){
  int blk=blockIdx.x;
  int c=blk&31, g=(blk>>5)&31, b=blk>>10;
  int lane=threadIdx.x, ch=lane>>2, sq=lane&3;
  int d=g*16+ch;
  float4 Ar = *(const float4*)(Alog + d*16 + sq*4);
  float A2[4];
  A2[0]=-__expf(Ar.x)*1.44269504088896f;
  A2[1]=-__expf(Ar.y)*1.44269504088896f;
  A2[2]=-__expf(Ar.z)*1.44269504088896f;
  A2[3]=-__expf(Ar.w)*1.44269504088896f;
  float Dv = Dp[d];
  __shared__ __align__(16) float dtxi[2][16][68];
  __shared__ __align__(16) float bc[2][32][33];
  __shared__ __align__(16) float pl[32][17];
  const int l0c = c*128;
  const size_t dtrow = ((size_t)(b*512)+d)*4096;
  const float* xb = xdbl + (size_t)b*4096*48;
  float4 rdt[2], rxi[2], rbc[4], rz[2][2];
  auto issue=[&](int t){
    int l0 = l0c + t*32;
    #pragma unroll
    for(int it=0; it<2; ++it){
      size_t o = dtrow + l0 + it*16 + sq*4;
      rdt[it]=*(const float4*)(dt+o);
      rxi[it]=*(const float4*)(xi+o);
    }
    #pragma unroll
    for(int k=0;k<4;k++){
      int j=(lane>>3)+k*8, seg=lane&7;
      rbc[k]=*(const float4*)(xb + (size_t)(l0+j)*48 + 16 + seg*4);
    }
    size_t eb = dtrow + l0 + sq*8;
    rz[t&1][0] = *(const float4*)(z+eb);
    rz[t&1][1] = *(const float4*)(z+eb+4);
  };
  auto store=[&](int buf){
    #pragma unroll
    for(int it=0;it<2;++it){
      int base = it*32 + sq*8;
      *(float4*)&dtxi[buf][ch][base]   = make_float4(rdt[it].x, rxi[it].x, rdt[it].y, rxi[it].y);
      *(float4*)&dtxi[buf][ch][base+4] = make_float4(rdt[it].z, rxi[it].z, rdt[it].w, rxi[it].w);
    }
    #pragma unroll
    for(int k=0;k<4;k++)
      *(float4*)&bc[buf][(lane>>3)+k*8][(lane&7)*4] = rbc[k];
  };
  float h[4];
  {
    float4 h0 = hstart[blk*64 + lane];
    h[0]=h0.x; h[1]=h0.y; h[2]=h0.z; h[3]=h0.w;
  }
  issue(0); store(0);
  for(int t=0;t<4;t++){
    int buf=t&1;
    if(t<3) issue(t+1);
    #pragma unroll 2
    for(int jp=0;jp<16;jp++){
      float4 dx = *(const float4*)&dtxi[buf][ch][jp*4];
      {
        int j=2*jp;
        float dtv=dx.x, u=dx.x*dx.y;
        float4 B4 = *(const float4*)&bc[buf][j][sq*4];
        float4 C4 = *(const float4*)&bc[buf][j][16+sq*4];
        float Bv[4]={B4.x,B4.y,B4.z,B4.w}, Cv[4]={C4.x,C4.y,C4.z,C4.w};
        float p;
        #pragma unroll
        for(int i=0;i<4;i++){ float dA=exp2f(dtv*A2[i]); h[i]=fmaf(dA,h[i],u*Bv[i]); }
        p = h[0]*Cv[0]; p=fmaf(h[1],Cv[1],p); p=fmaf(h[2],Cv[2],p); p=fmaf(h[3],Cv[3],p);
        p = quad_sum4(p);
        if(sq==0) pl[j][ch]=p;
      }
      {
        int j=2*jp+1;
        float dtv=dx.z, u=dx.z*dx.w;
        float4 B4 = *(const float4*)&bc[buf][j][sq*4];
        float4 C4 = *(const float4*)&bc[buf][j][16+sq*4];
        float Bv[4]={B4.x,B4.y,B4.z,B4.w}, Cv[4]={C4.x,C4.y,C4.z,C4.w};
        float p;
        #pragma unroll
        for(int i=0;i<4;i++){ float dA=exp2f(dtv*A2[i]); h[i]=fmaf(dA,h[i],u*Bv[i]); }
        p = h[0]*Cv[0]; p=fmaf(h[1],Cv[1],p); p=fmaf(h[2],Cv[2],p); p=fmaf(h[3],Cv[3],p);
        p = quad_sum4(p);
        if(sq==0) pl[j][ch]=p;
      }
    }
    // emit: lane covers (ch, steps sq*8..sq*8+7); z prefetched in issue(t)
    {
      int l0 = l0c + t*32;
      size_t eb = dtrow + l0 + sq*8;
      float zarr[8], yarr[8];
      *(float4*)&zarr[0]=rz[t&1][0]; *(float4*)&zarr[4]=rz[t&1][1];
      #pragma unroll
      for(int k=0;k<8;k++){
        int j=sq*8+k;
        float p = pl[j][ch];
        float xiv = dtxi[buf][ch][2*j+1];
        yarr[k] = (p + xiv*Dv) * silu_f(zarr[k]);
      }
      *(float4*)(y+eb)   = *(float4*)&yarr[0];
      *(float4*)(y+eb+4) = *(float4*)&yarr[4];
    }
    if(t<3) store(buf^1);
  }
}

// ---------------- fold out_w over the 4 direction groups: W'(64,512) ----------------
__global__ __launch_bounds__(256) void fold_w(const float* __restrict__ ow, float* __restrict__ wf){
  int i = blockIdx.x*256 + threadIdx.x;   // 32768
  if(i>=32768) return;
  int c = i>>9, d2 = i&511;
  wf[i] = ow[(c)*512+d2] + ow[(64+c)*512+d2] + ow[(128+c)*512+d2] + ow[(192+c)*512+d2];
}

// ---------------- GEMM: res = (y @ W'^T) * fo2s ; y (B,512,L), out res (B,64,L) ----------------
__global__ __launch_bounds__(256) void gemm_res(const float* __restrict__ y,
    const float* __restrict__ wf, const float* __restrict__ fo2s, float* __restrict__ res){
  int blk=blockIdx.x; int b=blk>>6, l0=(blk&63)<<6;
  __shared__ __align__(16) float a_t[64][64];
  __shared__ float wch[64][65];
  __shared__ float o_t[64][64];
  int t=threadIdx.x, lq=t>>4, cq=t&15;
  float acc[16];
  #pragma unroll
  for(int j=0;j<16;j++) acc[j]=0.f;
  for(int kc=0;kc<8;kc++){
    __syncthreads();
    for(int i=t;i<4096;i+=256){ int k=i>>6,l=i&63; a_t[k][l]=y[((size_t)(b*512)+kc*64+k)*4096 + l0+l]; }
    for(int i=t;i<4096;i+=256){ int r=i>>6,k=i&63; wch[r][k]=wf[r*512 + kc*64 + k]; }
    __syncthreads();
    for(int k=0;k<64;k++){
      const float4 uv = *(const float4*)&a_t[k][lq<<2];
      float uvf[4]; uvf[0]=uv.x; uvf[1]=uv.y; uvf[2]=uv.z; uvf[3]=uv.w;
      float wv[4];
      #pragma unroll
      for(int j=0;j<4;j++) wv[j]=wch[(cq<<2)+j][k];
      #pragma unroll
      for(int ii=0;ii<4;ii++)
        #pragma unroll
        for(int jj=0;jj<4;jj++)
          acc[ii*4+jj]=fmaf(uvf[ii],wv[jj],acc[ii*4+jj]);
    }
  }
  __syncthreads();
  #pragma unroll
  for(int ii=0;ii<4;ii++)
    #pragma unroll
    for(int jj=0;jj<4;jj++)
      o_t[(cq<<2)+jj][(lq<<2)+ii]=acc[ii*4+jj];
  __syncthreads();
  for(int i=t;i<4096;i+=256){
    int o=i>>6,l=i&63;
    size_t idx=((size_t)(b*64+o))*4096 + l0 + l;
    res[idx]=o_t[o][l]*fo2s[idx];
  }
}

// ---------------- per (b,c) spatial mean ----------------
__global__ __launch_bounds__(256) void colmean(const float* __restrict__ res, float* __restrict__ fm){
  int bc = blockIdx.x;
  const float* p = res + (size_t)bc*4096;
  float s=0;
  for(int i=threadIdx.x;i<4096;i+=256) s+=p[i];
  __shared__ float ls[256];
  ls[threadIdx.x]=s; __syncthreads();
  for(int st=128;st>0;st>>=1){ if(threadIdx.x<st) ls[threadIdx.x]+=ls[threadIdx.x+st]; __syncthreads(); }
  if(threadIdx.x==0) fm[bc]=ls[0]*(1.f/4096.f);
}

// ---------------- tiny mamba2 over channel sequence (L=64, d_model=2, d_inner=4) ----------------
__global__ __launch_bounds__(64) void mamba2_kernel(const float* __restrict__ fm,
    const float* __restrict__ in_w, const float* __restrict__ cw, const float* __restrict__ cb,
    const float* __restrict__ xp, const float* __restrict__ dtw, const float* __restrict__ dtb,
    const float* __restrict__ Alog, const float* __restrict__ Dp, const float* __restrict__ ow,
    float* __restrict__ fsum){
  int b = blockIdx.x; int t = threadIdx.x;   // 0..63
  __shared__ float xi0m[64][4], xim[64][4], dtm[64][4], xbl[64][33], ym[64][4];
  float a0 = fm[b*64+t], a1 = fm[b*64 + 63-t];
  float zreg[4];
  #pragma unroll
  for(int d2=0;d2<4;d2++){
    xi0m[t][d2] = in_w[d2*2+0]*a0 + in_w[d2*2+1]*a1;
    zreg[d2]    = in_w[(4+d2)*2+0]*a0 + in_w[(4+d2)*2+1]*a1;
  }
  __syncthreads();
  float xir[4];
  #pragma unroll
  for(int d2=0;d2<4;d2++){
    float acc=cb[d2];
    #pragma unroll
    for(int k=0;k<4;k++){
      int srow=t-3+k;
      if(srow>=0) acc += cw[d2*4+k]*xi0m[srow][d2];
    }
    xir[d2]=silu_f(acc);
    xim[t][d2]=xir[d2];
  }
  for(int j=0;j<33;j++){
    float acc=0;
    #pragma unroll
    for(int d2=0;d2<4;d2++) acc += xp[j*4+d2]*xir[d2];
    xbl[t][j]=acc;
  }
  #pragma unroll
  for(int d2=0;d2<4;d2++){
    float v = xbl[t][0]*dtw[d2] + dtb[d2];
    dtm[t][d2] = (v>20.f)? v : log1pf(__expf(v));
  }
  __syncthreads();
  int dd=t>>4, s=t&15;
  float A2 = -__expf(Alog[dd*16+s]) * 1.44269504088896f;
  float h=0.f;
  for(int c=0;c<64;c++){
    float dtv=dtm[c][dd];
    float dA=exp2f(dtv*A2);
    h = fmaf(dA, h, dtv*xim[c][dd]*xbl[c][1+s]);
    float p = h*xbl[c][17+s];
    p += __shfl_xor(p,1,16);
    p += __shfl_xor(p,2,16);
    p += __shfl_xor(p,4,16);
    p += __shfl_xor(p,8,16);
    if(s==0) ym[c][dd]=p;
  }
  __syncthreads();
  float os=0.f;
  #pragma unroll
  for(int d2=0;d2<4;d2++){
    float yv = (ym[t][d2] + xim[t][d2]*Dp[d2]) * silu_f(zreg[d2]);
    os += yv * (ow[d2] + ow[4+d2]);
  }
  fsum[b*64+t]=os;
}

// ---------------- foss = res*(1+foc) ; x2 = outproj(foss) + x ----------------
__global__ __launch_bounds__(256) void outproj_kernel(const float* __restrict__ res,
    const float* __restrict__ fsum, const float* __restrict__ opw, const float* __restrict__ opb,
    const float* __restrict__ x, float* __restrict__ x2){
  int bh=blockIdx.x; int b=bh>>6,h=bh&63;
  __shared__ float tile[64][64];
  __shared__ float wl[4096];
  for(int i=threadIdx.x;i<4096;i+=256) wl[i]=opw[i];
  for(int i=threadIdx.x;i<4096;i+=256){
    int c=i>>6,w=i&63;
    tile[c][w]=res[((size_t)(b*64+c))*4096 + h*64 + w]*(1.f+fsum[b*64+c]);
  }
  __syncthreads();
  int px=threadIdx.x&63, og=threadIdx.x>>6;
  float acc[16];
  #pragma unroll
  for(int j=0;j<16;j++) acc[j]=0.f;
  for(int c=0;c<64;c++){
    float v=tile[c][px];
    #pragma unroll
    for(int j=0;j<16;j++) acc[j]=fmaf(wl[(og*16+j)*64+c],v,acc[j]);
  }
  for(int j=0;j<16;j++){
    int o=og*16+j;
    size_t idx=((size_t)(b*64+o))*4096 + h*64 + px;
    x2[idx]=acc[j]+opb[o]+x[idx];
  }
}

// ---------------- LN2 apply + ffn_in (64->256) ----------------
__global__ __launch_bounds__(256) void ffn_in_kernel(const float* __restrict__ x2,
    const float* __restrict__ n2w, const float* __restrict__ n2b,
    const float* __restrict__ fiw, const float* __restrict__ fib,
    const float* __restrict__ mu2, const float* __restrict__ rstd2,
    float* __restrict__ g){
  int bh=blockIdx.x; int b=bh>>6,h=bh&63;
  __shared__ float tile[64][64];
  __shared__ float wl[256*64];
  float m=mu2[b], rs=rstd2[b];
  for(int i=threadIdx.x;i<4096;i+=256){
    int c=i>>6,w=i&63;
    size_t sp=(size_t)c*4096 + h*64 + w;
    tile[c][w]=(x2[(size_t)b*262144+sp]-m)*rs*n2w[sp]+n2b[sp];
  }
  for(int i=threadIdx.x;i<16384;i+=256) wl[i]=fiw[i];
  __syncthreads();
  int px=threadIdx.x&63, og=threadIdx.x>>6;
  for(int half=0;half<2;half++){
    float acc[32];
    #pragma unroll
    for(int j=0;j<32;j++) acc[j]=0.f;
    int ob = half*128 + og*32;
    for(int c=0;c<64;c++){
      float v=tile[c][px];
      #pragma unroll
      for(int j=0;j<32;j++) acc[j]=fmaf(wl[(ob+j)*64+c],v,acc[j]);
    }
    for(int j=0;j<32;j++){
      int o=ob+j;
      g[((size_t)(b*256+o))*4096 + h*64 + px]=acc[j]+fib[o];
    }
  }
}

// ---------------- ffn depthwise 3x3 + gelu-gate ----------------
__global__ __launch_bounds__(256) void ffn_dw_gate(const float* __restrict__ g,
    const float* __restrict__ dww, const float* __restrict__ dwb, float* __restrict__ gm){
  int e = blockIdx.x*256 + threadIdx.x;   // 4*128*4096
  int sp = e & 4095, j = (e>>12)&127, b = e>>19;
  int h = sp>>6, w = sp&63;
  float v[2];
  #pragma unroll
  for(int half=0;half<2;half++){
    int ch = j + half*128;
    const float* gp = g + ((size_t)(b*256+ch))*4096;
    float acc = dwb[ch];
    #pragma unroll
    for(int kh=0;kh<3;kh++){
      int ih=h+kh-1; if(ih<0||ih>63) continue;
      #pragma unroll
      for(int kw=0;kw<3;kw++){
        int iw=w+kw-1; if(iw<0||iw>63) continue;
        acc += dww[ch*9+kh*3+kw]*gp[ih*64+iw];
      }
    }
    v[half]=acc;
  }
  float ge = 0.5f*v[0]*(1.f+erff(v[0]*0.70710678f));
  gm[((size_t)(b*128+j))*4096 + sp] = ge*v[1];
}

// ---------------- ffn_out (128->64) + bias + residual add -> d_out ----------------
__global__ __launch_bounds__(256) void ffn_out_kernel(const float* __restrict__ gm,
    const float* __restrict__ fow, const float* __restrict__ fob,
    const float* __restrict__ x2, float* __restrict__ out){
  int bh=blockIdx.x; int b=bh>>6,h=bh&63;
  __shared__ float tile[128][64];
  __shared__ float wl[64*128];
  for(int i=threadIdx.x;i<8192;i+=256){
    int c=i>>6,w=i&63;
    tile[c][w]=gm[((size_t)(b*128+c))*4096 + h*64 + w];
  }
  for(int i=threadIdx.x;i<8192;i+=256) wl[i]=fow[i];
  __syncthreads();
  int px=threadIdx.x&63, og=threadIdx.x>>6;
  float acc[16];
  #pragma unroll
  for(int j=0;j<16;j++) acc[j]=0.f;
  for(int c=0;c<128;c++){
    float v=tile[c][px];
    #pragma unroll
    for(int j=0;j<16;j++) acc[j]=fmaf(wl[(og*16+j)*128+c],v,acc[j]);
  }
  for(int j=0;j<16;j++){
    int o=og*16+j;
    size_t idx=((size_t)(b*64+o))*4096 + h*64 + px;
    out[idx]=acc[j]+fob[o]+x2[idx];
  }
}

extern "C" void kernel_launch(void* const* d_in, const int* in_sizes, int n_in,
                              void* d_out, int out_size, void* d_ws, size_t ws_size,
                              hipStream_t stream){
  const float* x      = (const float*)d_in[0];
  const float* n1w    = (const float*)d_in[1];
  const float* n1b    = (const float*)d_in[2];
  const float* n2w    = (const float*)d_in[3];
  const float* n2b    = (const float*)d_in[4];
  const float* ipw    = (const float*)d_in[5];
  const float* ipb    = (const float*)d_in[6];
  const float* dww    = (const float*)d_in[7];
  const float* dwb    = (const float*)d_in[8];
  const float* opw    = (const float*)d_in[9];
  const float* opb    = (const float*)d_in[10];
  const float* m1_inw = (const float*)d_in[11];
  const float* m1_cw  = (const float*)d_in[12];
  const float* m1_cb  = (const float*)d_in[13];
  const float* m1_xp  = (const float*)d_in[14];
  const float* m1_dtw = (const float*)d_in[15];
  const float* m1_dtb = (const float*)d_in[16];
  const float* m1_Al  = (const float*)d_in[17];
  const float* m1_D   = (const float*)d_in[18];
  const float* m1_ow  = (const float*)d_in[19];
  const float* m2_inw = (const float*)d_in[20];
  const float* m2_cw  = (const float*)d_in[21];
  const float* m2_cb  = (const float*)d_in[22];
  const float* m2_xp  = (const float*)d_in[23];
  const float* m2_dtw = (const float*)d_in[24];
  const float* m2_dtb = (const float*)d_in[25];
  const float* m2_Al  = (const float*)d_in[26];
  const float* m2_D   = (const float*)d_in[27];
  const float* m2_ow  = (const float*)d_in[28];
  const float* fiw    = (const float*)d_in[29];
  const float* fib    = (const float*)d_in[30];
  const float* fdw    = (const float*)d_in[31];
  const float* fdb    = (const float*)d_in[32];
  const float* fow    = (const float*)d_in[33];
  const float* fob    = (const float*)d_in[34];
  float* out = (float*)d_out;
  float* ws  = (float*)d_ws;

  // workspace layout (floats), aliased.
  float* mu1   = ws + 0;  float* rstd1 = ws + 4;
  float* mu2   = ws + 8;  float* rstd2 = ws + 12;
  float* fmean = ws + 64;    // 256
  float* fsum  = ws + 320;   // 256
  float* wfold = ws + 1024;  // 32768
  float* lnpart= ws + 33792; // 512 floats (256 float2)
  float* fo1raw= ws + 36864;           // 1M   (later: hstart, then res)
  float* fo2s  = fo1raw + 1048576;     // 1M
  float* fo1s  = fo2s   + 1048576;     // 1M  (later: Pbuf)
  float* fo1t  = fo1s   + 1048576;     // 1M  (later: qbuf)
  float* ubuf  = fo1t   + 1048576;     // (u_bf16; later dt 8M; later g 4M)
  float* dtbuf = ubuf;                 // (B,512,L)
  float* gbuf  = ubuf;                 // (B,256,L)
  float* xi0   = ubuf + 8388608;       // 8M  (later: y)
  float* ybuf  = xi0;
  float* zbuf  = xi0  + 8388608;       // 8M  (later: gm 2M)
  float* gmbuf = zbuf;
  float* xibuf = zbuf + 8388608;       // 8M
  float* xdbl  = xibuf+ 8388608;       // 786432
  float* x2    = xdbl + 786432;        // 1M
  float* res   = fo1raw;
  float* Pbuf   = fo1s;     // 4096 blk * 64 lane * 4 = 1,048,576 floats exactly
  float* qbuf   = fo1t;
  float* hstart = fo1raw;   // free between dwconv and gemm_res
  uint*   u_bf  = (uint*)ubuf;               // (B,4096,256) bf16 = 8MB
  ushort* w_bf  = (ushort*)(x2 + 1048576);   // 1024x256 bf16 = 512KB (tail)

  hipLaunchKernelGGL(ln_part, dim3(256), dim3(256), 0, stream, x, (float2*)lnpart);
  hipLaunchKernelGGL(ln_fin, dim3(4), dim3(64), 0, stream, (const float2*)lnpart, mu1, rstd1);
  hipLaunchKernelGGL(cvt_w_bf, dim3(512), dim3(256), 0, stream, m1_inw, (uint*)w_bf);
  hipLaunchKernelGGL(ln1_inproj, dim3(256), dim3(256), 0, stream,
                     x, n1w, n1b, ipw, ipb, mu1, rstd1, fo1raw, fo2s);
  hipLaunchKernelGGL(dwconv_silu_tr, dim3(256), dim3(256), 0, stream,
                     fo1raw, dww, dwb, fo1s, fo1t);
  hipLaunchKernelGGL(gather_u_t, dim3(1024), dim3(256), 0, stream, fo1s, fo1t, u_bf);
  hipLaunchKernelGGL(gemm_xz_mfma, dim3(128, 8), dim3(256), 0, stream,
                     (const ushort*)u_bf, w_bf, xi0, zbuf);
  hipLaunchKernelGGL(conv1d_silu, dim3(32768), dim3(256), 0, stream, xi0, m1_cw, m1_cb, xibuf);
  hipLaunchKernelGGL(gemm_xdbl, dim3(256), dim3(256), 0, stream, xibuf, m1_xp, xdbl);
  hipLaunchKernelGGL(dtproj, dim3(256), dim3(256), 0, stream, xdbl, m1_dtw, m1_dtb, dtbuf);
  hipLaunchKernelGGL(fold_w, dim3(128), dim3(256), 0, stream, m1_ow, wfold);
  hipLaunchKernelGGL(scan3_p1, dim3(4096), dim3(64), 0, stream,
                     dtbuf, xibuf, xdbl, m1_Al, (float4*)Pbuf, (float4*)qbuf);
  hipLaunchKernelGGL(scan3_mid, dim3(32), dim3(256), 0, stream,
                     (const float4*)Pbuf, (const float4*)qbuf, (float4*)hstart);
  hipLaunchKernelGGL(scan3_p2, dim3(4096), dim3(64), 0, stream,
                     dtbuf, xibuf, zbuf, xdbl, m1_Al, m1_D, (const float4*)hstart, ybuf);
  hipLaunchKernelGGL(gemm_res, dim3(256), dim3(256), 0, stream, ybuf, wfold, fo2s, res);
  hipLaunchKernelGGL(colmean, dim3(256), dim3(256), 0, stream, res, fmean);
  hipLaunchKernelGGL(mamba2_kernel, dim3(4), dim3(64), 0, stream,
                     fmean, m2_inw, m2_cw, m2_cb, m2_xp, m2_dtw, m2_dtb, m2_Al, m2_D, m2_ow, fsum);
  hipLaunchKernelGGL(outproj_kernel, dim3(256), dim3(256), 0, stream,
                     res, fsum, opw, opb, x, x2);
  hipLaunchKernelGGL(ln_part, dim3(256), dim3(256), 0, stream, x2, (float2*)lnpart);
  hipLaunchKernelGGL(ln_fin, dim3(4), dim3(64), 0, stream, (const float2*)lnpart, mu2, rstd2);
  hipLaunchKernelGGL(ffn_in_kernel, dim3(256), dim3(256), 0, stream,
                     x2, n2w, n2b, fiw, fib, mu2, rstd2, gbuf);
  hipLaunchKernelGGL(ffn_dw_gate, dim3(8192), dim3(256), 0, stream, gbuf, fdw, fdb, gmbuf);
  hipLaunchKernelGGL(ffn_out_kernel, dim3(256), dim3(256), 0, stream, gmbuf, fow, fob, x2, out);
}